// Round 1
// 1298.682 us; speedup vs baseline: 1.1248x; 1.1248x over previous
//
#include <hip/hip_runtime.h>
#include <hip/hip_bf16.h>
#include <math.h>

#define EPS 1e-5f
#define XAS 97
#define QS 17
#define SS 65

typedef __attribute__((ext_vector_type(8))) short short8;
typedef __attribute__((ext_vector_type(4))) float f32x4;

__device__ __forceinline__ float gelu_f(float x){
    return 0.5f*x*(1.0f+erff(x*0.7071067811865475f));
}
__device__ __forceinline__ float sigmoid_f(float x){
    return 1.0f/(1.0f+__expf(-x));
}
// row (wi*64+n) -> b*32768 + voxel   (window order b,d,h,w ; in-window order wd,wh,ww)
__device__ __forceinline__ int row_to_bv(int r){
    int wi = r >> 6, n = r & 63;
    int b = wi >> 9, rem = wi & 511;
    int zd = rem >> 6, yh = (rem >> 3) & 7, xw = rem & 7;
    int wz = n >> 4, wy = (n >> 2) & 3, wx = n & 3;
    int Dz = (zd<<2)+wz, Hy = (yh<<2)+wy, Wx = (xw<<2)+wx;
    return (b<<15) + (Dz<<10) + (Hy<<5) + Wx;
}
__device__ __forceinline__ int relidx(int i,int j){
    int zi=i>>4, yi=(i>>2)&3, xi=i&3;
    int zj=j>>4, yj=(j>>2)&3, xj=j&3;
    return ((zi-zj+3)*7+(yi-yj+3))*7+(xi-xj+3);
}

// ---------------- Kprep1: combined weight [288][192] -> hi/lo bf16 split ----------------
// WT[n][k] = (n<96 ? w_pattn[k][n] : w_pcnn[k][n-96]) as hi + lo bf16 pair.
__global__ __launch_bounds__(256) void kprep1(const float* __restrict__ w1,
    const float* __restrict__ w2, __hip_bfloat16* __restrict__ WThi,
    __hip_bfloat16* __restrict__ WTlo)
{
    int i=blockIdx.x*256+threadIdx.x;   // 288*192 = 55296 exactly
    int n=i/192, k=i-n*192;
    float v=(n<96)? w1[k*96+n] : w2[k*192+(n-96)];
    __hip_bfloat16 hb=__float2bfloat16(v);
    WThi[i]=hb;
    WTlo[i]=__float2bfloat16(v-__bfloat162float(hb));
}

// ---------------- K1: dual GEMM (192->96 & 192->192) via split-bf16 MFMA + both LNs --------
// C[m][n] = sum_k x[m][k]*WT[n][k], fp32-accurate via 3-term split:
//   Ahi*Bhi + Ahi*Blo + Alo*Bhi  (dropped Alo*Blo ~ 2^-16 rel).
// Block: 64 rows, 4 waves; wave w owns m-tile rows [w*16, w*16+16) x all 18 n-tiles.
// A staged in LDS as hi/lo bf16, rows padded to 200 shorts (400B stride -> 2-way bank
// aliasing on ds_read_b128, free). B frags read straight from L2 (k9b pattern).
__global__ __launch_bounds__(256) void k1_mfma(const float* __restrict__ x,
    const __hip_bfloat16* __restrict__ WThi, const __hip_bfloat16* __restrict__ WTlo,
    const float* __restrict__ b1, const float* __restrict__ g1, const float* __restrict__ bb1,
    const float* __restrict__ b2, const float* __restrict__ g2, const float* __restrict__ bb2,
    float* __restrict__ xa, float* __restrict__ vol)
{
    __shared__ short xhi[64*200];
    __shared__ short xlo[64*200];
    int tid=threadIdx.x;
    int row0=blockIdx.x*64;
    // stage + split-convert: 64 rows x 192 cols, 8 cols per unit => 1536 units
    for(int u=tid; u<1536; u+=256){
        int r=u/24, kc=(u-r*24)*8;
        const float* src=x + ((size_t)(row0+r))*192 + kc;
        float v[8];
        *(f32x4*)&v[0]=*(const f32x4*)(src);
        *(f32x4*)&v[4]=*(const f32x4*)(src+4);
        union { short8 v8; __hip_bfloat16 b[8]; } uh, ul;
        #pragma unroll
        for(int j2=0;j2<8;j2++){
            __hip_bfloat16 hb=__float2bfloat16(v[j2]);
            uh.b[j2]=hb;
            ul.b[j2]=__float2bfloat16(v[j2]-__bfloat162float(hb));
        }
        *(short8*)&xhi[r*200+kc]=uh.v8;
        *(short8*)&xlo[r*200+kc]=ul.v8;
    }
    __syncthreads();
    int wave=tid>>6, lane=tid&63, quad=lane>>4, l16=lane&15;
    const short* Whi=(const short*)WThi;
    const short* Wlo=(const short*)WTlo;
    f32x4 acc[18];
    #pragma unroll
    for(int j=0;j<18;j++) acc[j]=(f32x4){0.f,0.f,0.f,0.f};
    int arow=wave*16+l16;
    #pragma unroll
    for(int t=0;t<6;t++){
        int k0=t*32+quad*8;
        short8 ahi=*(const short8*)&xhi[arow*200+k0];
        short8 alo=*(const short8*)&xlo[arow*200+k0];
        #pragma unroll
        for(int j=0;j<18;j++){
            short8 bhi=*(const short8*)(Whi+(size_t)(j*16+l16)*192+k0);
            short8 blo=*(const short8*)(Wlo+(size_t)(j*16+l16)*192+k0);
            acc[j]=__builtin_amdgcn_mfma_f32_16x16x32_bf16(ahi,bhi,acc[j],0,0,0);
            acc[j]=__builtin_amdgcn_mfma_f32_16x16x32_bf16(ahi,blo,acc[j],0,0,0);
            acc[j]=__builtin_amdgcn_mfma_f32_16x16x32_bf16(alo,bhi,acc[j],0,0,0);
        }
    }
    // ---- epilogue: bias + dual LayerNorm, fully in-register ----
    // lane holds rows (wave*16 + quad*4 + reg), col = j*16 + l16
    float bias[18];
    #pragma unroll
    for(int j=0;j<18;j++){ int c=j*16+l16; bias[j]=(c<96)? b1[c] : b2[c-96]; }
    #pragma unroll
    for(int reg=0; reg<4; reg++){
        int grow=row0 + wave*16 + quad*4 + reg;
        // attention half: cols 0..95 (n-tiles 0..5), LN over 96
        float va[6];
        float s=0.f, ss=0.f;
        #pragma unroll
        for(int j=0;j<6;j++){ float v=acc[j][reg]+bias[j]; va[j]=v; s+=v; ss+=v*v; }
        #pragma unroll
        for(int o=1;o<16;o<<=1){ s+=__shfl_xor(s,o); ss+=__shfl_xor(ss,o); }
        float m=s*(1.f/96.f), var=ss*(1.f/96.f)-m*m, rstd=rsqrtf(var+EPS);
        #pragma unroll
        for(int j=0;j<6;j++){
            int c=j*16+l16;
            xa[(size_t)grow*96+c]=(va[j]-m)*rstd*g1[c]+bb1[c];
        }
        // cnn half: cols 96..287 (n-tiles 6..17), LN over 192 -> scatter NDHWC
        float vc[12];
        s=0.f; ss=0.f;
        #pragma unroll
        for(int j=0;j<12;j++){ float v=acc[6+j][reg]+bias[6+j]; vc[j]=v; s+=v; ss+=v*v; }
        #pragma unroll
        for(int o=1;o<16;o<<=1){ s+=__shfl_xor(s,o); ss+=__shfl_xor(ss,o); }
        float m2=s*(1.f/192.f), var2=ss*(1.f/192.f)-m2*m2, rstd2=rsqrtf(var2+EPS);
        int bv=row_to_bv(grow);
        #pragma unroll
        for(int j=0;j<12;j++){
            int c=j*16+l16;
            vol[(size_t)bv*192+c]=(vc[j]-m2)*rstd2*g2[c]+bb2[c];
        }
    }
}

// ---------------- K2: depthwise 3x3x3 conv, NDHWC, slide along W ----------------
__global__ __launch_bounds__(192) void k2_dwconv(const float* __restrict__ vin,
        const float* __restrict__ wd_, const float* __restrict__ bd,
        float* __restrict__ vout)
{
    int c=threadIdx.x;
    int blk=blockIdx.x;
    int Hy=blk&31, Dz=(blk>>5)&31, b=blk>>10;
    float wreg[27];
    #pragma unroll
    for(int t=0;t<27;t++) wreg[t]=wd_[c*27+t];
    float bias=bd[c];
    const float* base=vin + ((size_t)b<<15)*192;
    int voff[9]; bool vld[9];
    #pragma unroll
    for(int i=0;i<9;i++){
        int zz=Dz+i/3-1, yy=Hy+i%3-1;
        vld[i]=(zz>=0&&zz<32&&yy>=0&&yy<32);
        voff[i]=(zz<<10)+(yy<<5);
    }
    float prv[9],cur[9],nxt[9];
    #pragma unroll
    for(int i=0;i<9;i++){
        prv[i]=0.f;
        cur[i]= vld[i]? base[(size_t)(voff[i])*192+c]   : 0.f;
        nxt[i]= vld[i]? base[(size_t)(voff[i]+1)*192+c] : 0.f;
    }
    size_t obase=((size_t)((b<<15)+(Dz<<10)+(Hy<<5)))*192 + c;
    for(int wx=0;wx<32;wx++){
        float o=bias;
        #pragma unroll
        for(int i=0;i<9;i++) o += prv[i]*wreg[i*3] + cur[i]*wreg[i*3+1] + nxt[i]*wreg[i*3+2];
        vout[obase + (size_t)wx*192] = o;
        #pragma unroll
        for(int i=0;i<9;i++){ prv[i]=cur[i]; cur[i]=nxt[i]; }
        int wn=wx+2;
        #pragma unroll
        for(int i=0;i<9;i++) nxt[i]=(vld[i]&&wn<32)? base[(size_t)(voff[i]+wn)*192+c] : 0.f;
    }
}

// ---------------- K3: instance-norm partial sums over spatial (per b,c) ----------------
__global__ __launch_bounds__(192) void k3_stats(const float* __restrict__ v,
      float* __restrict__ sum, float* __restrict__ sumsq)
{
    int c=threadIdx.x;
    int chunk=blockIdx.x, b=blockIdx.y;
    float s=0.f,ss=0.f;
    const float* p = v + (((size_t)b<<15) + (size_t)chunk*256)*192 + c;
    for(int i=0;i<256;i++){ float t=p[(size_t)i*192]; s+=t; ss+=t*t; }
    atomicAdd(&sum[b*192+c], s);
    atomicAdd(&sumsq[b*192+c], ss);
}

__global__ void k_finalize(const float* __restrict__ sum, const float* __restrict__ sumsq,
                           float* __restrict__ mean, float* __restrict__ rstd, int n, float inv)
{
    int i = blockIdx.x*blockDim.x + threadIdx.x;
    if(i<n){ float m=sum[i]*inv; float v=sumsq[i]*inv - m*m; mean[i]=m; rstd[i]=rsqrtf(v+EPS); }
}

// ---------------- K4: in-place inorm+gelu + pooled partials ----------------
__global__ __launch_bounds__(192) void k4_apply(float* __restrict__ v,
      const float* __restrict__ mean, const float* __restrict__ rstd, float* __restrict__ pooled)
{
    int c=threadIdx.x; int chunk=blockIdx.x, b=blockIdx.y;
    float m=mean[b*192+c], r=rstd[b*192+c];
    float s=0.f;
    float* p = v + (((size_t)b<<15)+(size_t)chunk*256)*192 + c;
    for(int i=0;i<256;i++){
        float t=(p[(size_t)i*192]-m)*r;
        t=gelu_f(t);
        p[(size_t)i*192]=t; s+=t;
    }
    atomicAdd(&pooled[b*192+c], s);
}

// ---------------- K4b: channel-interaction MLP -> sigmoid gate ----------------
__global__ __launch_bounds__(128) void k4b_gate(const float* __restrict__ pooled,
   const float* __restrict__ w1,const float* __restrict__ b1,
   const float* __restrict__ w2,const float* __restrict__ b2, float* __restrict__ gate)
{
    __shared__ float pm[192];
    __shared__ float h[24];
    int b=blockIdx.x, t=threadIdx.x;
    for(int i=t;i<192;i+=128) pm[i]=pooled[b*192+i]*(1.f/32768.f);
    __syncthreads();
    if(t<24){ float a=b1[t]; for(int k=0;k<192;k++) a+=pm[k]*w1[k*24+t]; h[t]=gelu_f(a); }
    __syncthreads();
    if(t<96){ float a=b2[t]; for(int j=0;j<24;j++) a+=h[j]*w2[j*96+t]; gate[b*96+t]=sigmoid_f(a); }
}

// ---------------- Kqkv: QKV GEMM (K=96), q*0.25 and v*gate folded, bf16 out ----------------
__global__ __launch_bounds__(256) void kqkv(const float* __restrict__ xa,
    const float* __restrict__ w, const float* __restrict__ bias,
    const float* __restrict__ gate, __hip_bfloat16* __restrict__ qkv)
{
    __shared__ float xs[32*96];
    __shared__ float ws[32*288];
    int tid=threadIdx.x; int row0=blockIdx.x*32;
    for(int i=tid;i<32*96;i+=256) xs[i]=xa[(size_t)row0*96+i];
    float acc[4][9]={};
    int cbase=tid&31, rbase=(tid>>5)<<2;
    for(int k0=0;k0<96;k0+=32){
        __syncthreads();
        for(int i=tid;i<32*288;i+=256){int kk=i/288,cc=i-kk*288; ws[i]=w[(k0+kk)*288+cc];}
        __syncthreads();
        for(int kk=0;kk<32;kk++){
            float a0=xs[(rbase+0)*96+k0+kk],a1=xs[(rbase+1)*96+k0+kk],
                  a2=xs[(rbase+2)*96+k0+kk],a3=xs[(rbase+3)*96+k0+kk];
            #pragma unroll
            for(int j=0;j<9;j++){
                float wv=ws[kk*288+cbase+32*j];
                acc[0][j]+=a0*wv;acc[1][j]+=a1*wv;acc[2][j]+=a2*wv;acc[3][j]+=a3*wv;
            }
        }
    }
    #pragma unroll
    for(int a=0;a<4;a++){
        int row=row0+rbase+a; int wi=row>>6, n=row&63, b=row>>15;
        #pragma unroll
        for(int j=0;j<9;j++){
            int col=cbase+32*j;
            float v=acc[a][j]+bias[col];
            int which=col/96, rem=col-which*96;
            int hh=rem>>4, e=rem&15;
            if(which==0) v*=0.25f;
            else if(which==2) v*=gate[b*96+rem];
            qkv[((size_t)(wi*18+which*6+hh)<<10) + (n<<4) + e]=__float2bfloat16(v);
        }
    }
}

// ---------------- K6: windowed attention (per window, loop heads) ----------------
__global__ __launch_bounds__(256) void k6_attn(const __hip_bfloat16* __restrict__ qkv,
    const float* __restrict__ rpb, float* __restrict__ ato)
{
    __shared__ float sq[64*QS], sk[64*QS], sv[64*QS];
    __shared__ float sS[64*SS];
    int tid=threadIdx.x;
    int wi=blockIdx.x;
    for(int h=0;h<6;h++){
        __syncthreads();
        for(int i=tid;i<3*1024;i+=256){
            int which=i>>10, r=i&1023; int n=r>>4, e=r&15;
            float val=__bfloat162float(qkv[((size_t)(wi*18+which*6+h)<<10) + r]);
            if(which==0) sq[n*QS+e]=val; else if(which==1) sk[n*QS+e]=val; else sv[n*QS+e]=val;
        }
        __syncthreads();
        {   // S = qk^T + bias : 4x4 tiles
            int ti=tid>>4, tj=tid&15;
            int i0=ti*4, j0=tj*4;
            float a[4][4]={};
            #pragma unroll
            for(int e=0;e<16;e++){
                float qv[4], kv[4];
                #pragma unroll
                for(int ii=0;ii<4;ii++) qv[ii]=sq[(i0+ii)*QS+e];
                #pragma unroll
                for(int jj=0;jj<4;jj++) kv[jj]=sk[(j0+jj)*QS+e];
                #pragma unroll
                for(int ii=0;ii<4;ii++)
                    #pragma unroll
                    for(int jj=0;jj<4;jj++) a[ii][jj]+=qv[ii]*kv[jj];
            }
            #pragma unroll
            for(int ii=0;ii<4;ii++)
                #pragma unroll
                for(int jj=0;jj<4;jj++)
                    sS[(i0+ii)*SS+j0+jj]=a[ii][jj]+rpb[relidx(i0+ii,j0+jj)*6+h];
        }
        __syncthreads();
        {   // softmax rows (4 lanes per row)
            int i=tid>>2, j0=(tid&3)<<4;
            float mx=-1e30f;
            for(int jj=0;jj<16;jj++) mx=fmaxf(mx,sS[i*SS+j0+jj]);
            for(int o=1;o<4;o<<=1) mx=fmaxf(mx,__shfl_xor(mx,o));
            float sum=0.f;
            for(int jj=0;jj<16;jj++){float p=__expf(sS[i*SS+j0+jj]-mx); sS[i*SS+j0+jj]=p; sum+=p;}
            for(int o=1;o<4;o<<=1) sum+=__shfl_xor(sum,o);
            float inv=1.f/sum;
            for(int jj=0;jj<16;jj++) sS[i*SS+j0+jj]*=inv;
        }
        __syncthreads();
        {   // O = P @ v
            int i=tid&63, e0=(tid>>6)<<2;
            float o0=0.f,o1=0.f,o2=0.f,o3=0.f;
            for(int j=0;j<64;j++){
                float p=sS[i*SS+j];
                o0+=p*sv[j*QS+e0];o1+=p*sv[j*QS+e0+1];o2+=p*sv[j*QS+e0+2];o3+=p*sv[j*QS+e0+3];
            }
            float* dst=&ato[((size_t)(wi*64+i))*96 + (h<<4) + e0];
            dst[0]=o0;dst[1]=o1;dst[2]=o2;dst[3]=o3;
        }
    }
}

// ---------------- K5: 1x1 conv 192->96 (post-gelu volume) ----------------
__global__ __launch_bounds__(256) void k5_pj(const float* __restrict__ vin,
    const float* __restrict__ w, const float* __restrict__ bias, float* __restrict__ out)
{
    __shared__ float xs[32*192];
    __shared__ float ws[32*96];
    int tid=threadIdx.x; int row0=blockIdx.x*32;
    for(int i=tid;i<32*192;i+=256) xs[i]=vin[(size_t)row0*192+i];
    float acc[4][3]={};
    int cbase=tid&31, rbase=(tid>>5)<<2;
    for(int k0=0;k0<192;k0+=32){
        __syncthreads();
        for(int i=tid;i<32*96;i+=256){ int kk=i/96, cc=i-kk*96; ws[i]=w[(k0+kk)*96+cc]; }
        __syncthreads();
        for(int kk=0;kk<32;kk++){
            float a0=xs[(rbase+0)*192+k0+kk], a1=xs[(rbase+1)*192+k0+kk],
                  a2=xs[(rbase+2)*192+k0+kk], a3=xs[(rbase+3)*192+k0+kk];
            #pragma unroll
            for(int j=0;j<3;j++){
                float wv=ws[kk*96+cbase+32*j];
                acc[0][j]+=a0*wv; acc[1][j]+=a1*wv; acc[2][j]+=a2*wv; acc[3][j]+=a3*wv;
            }
        }
    }
    #pragma unroll
    for(int a=0;a<4;a++){
        #pragma unroll
        for(int j=0;j<3;j++){
            int cc=cbase+32*j;
            out[(size_t)(row0+rbase+a)*96+cc]=acc[a][j]+bias[cc];
        }
    }
}

// ---------------- K7a: spatial-interaction conv1 (96->12) + stats ----------------
__global__ __launch_bounds__(192) void k7a_si(const float* __restrict__ ato,
    const float* __restrict__ w1, const float* __restrict__ b1,
    float* __restrict__ si12, float* __restrict__ siSum, float* __restrict__ siSumsq)
{
    __shared__ float sa[64*XAS];
    __shared__ float sw[96*12];
    __shared__ float red[24];
    int tid=threadIdx.x, wi=blockIdx.x, b=wi>>9;
    for(int i=tid;i<64*96;i+=192){ int n=i/96,c=i-n*96; sa[n*XAS+c]=ato[((size_t)(wi*64+n))*96+c]; }
    for(int i=tid;i<96*12;i+=192) sw[i]=w1[i];
    if(tid<24) red[tid]=0.f;
    __syncthreads();
    #pragma unroll
    for(int j=0;j<4;j++){
        int o=tid+192*j; int n=o/12, cc=o-n*12;
        float a=b1[cc];
        for(int k=0;k<96;k++) a+=sa[n*XAS+k]*sw[k*12+cc];
        atomicAdd(&red[cc],a);
        atomicAdd(&red[12+cc],a*a);
        int bv=row_to_bv(wi*64+n);
        si12[(size_t)bv*12+cc]=a;
    }
    __syncthreads();
    if(tid<12){ atomicAdd(&siSum[b*12+tid],red[tid]); atomicAdd(&siSumsq[b*12+tid],red[12+tid]); }
}

// ---------------- K7d: inorm+gelu on si12, conv2 (12->1), sigmoid ----------------
__global__ __launch_bounds__(256) void k7d_sig(const float* __restrict__ si12,
  const float* __restrict__ mean, const float* __restrict__ rstd,
  const float* __restrict__ w2, const float* __restrict__ b2, float* __restrict__ sig)
{
    int bv=blockIdx.x*256+threadIdx.x;
    int b=bv>>15;
    float a=b2[0];
    #pragma unroll
    for(int c=0;c<12;c++){
        float t=(si12[(size_t)bv*12+c]-mean[b*12+c])*rstd[b*12+c];
        a+=gelu_f(t)*w2[c];
    }
    sig[bv]=sigmoid_f(a);
}

// ---------------- K8: stats of sigmoid(si)*PJ (per b,c of 96) ----------------
__global__ __launch_bounds__(192) void k8_gstats(const float* __restrict__ pj,
   const float* __restrict__ sig, float* __restrict__ gSum, float* __restrict__ gSumsq)
{
    int tid=threadIdx.x; int c=tid%96, vh=tid/96;
    int chunk=blockIdx.x, b=blockIdx.y;
    float s=0.f,ss=0.f;
    for(int i=0;i<128;i++){
        int v=chunk*256 + i*2 + vh;
        int bv=(b<<15)+v;
        float t=sig[bv]*pj[(size_t)bv*96+c];
        s+=t; ss+=t*t;
    }
    atomicAdd(&gSum[b*96+c],s); atomicAdd(&gSumsq[b*96+c],ss);
}

// ---------------- Kprep: w_proj (192x192 f32, [k][n]) -> WT bf16 [n][k] ----------------
__global__ __launch_bounds__(256) void kprep(const float* __restrict__ wp,
                                             __hip_bfloat16* __restrict__ WT)
{
    int i=blockIdx.x*256+threadIdx.x;     // 36864 total
    int n=i/192, k=i-n*192;
    WT[n*192+k]=__float2bfloat16(wp[k*192+n]);
}

// ---------------- K9a2: LN(attn) + gated-inorm -> U (bf16, in-place over ATO) ----------------
// Row r: reads ato[r*96 .. r*96+96) (f32, 384B) and writes U row r as 192 bf16 over the
// SAME 384 bytes. The 8 lanes owning a row are in one wave; all f32 loads are issued
// before any bf16 store in program order -> wave-lockstep safe.
__global__ __launch_bounds__(256) void k9a2_gather(float* atoU,
  const float* __restrict__ pj, const float* __restrict__ sig,
  const float* __restrict__ gMean, const float* __restrict__ gRstd,
  const float* __restrict__ ga, const float* __restrict__ bba)
{
    int tid=threadIdx.x; int row0=blockIdx.x*32;
    int rr=tid>>3, part=tid&7;
    int r=row0+rr;
    __hip_bfloat16* U=(__hip_bfloat16*)atoU;
    float av[12];
    #pragma unroll
    for(int j=0;j<12;j++) av[j]=atoU[(size_t)r*96+part*12+j];
    float s=0.f, ss=0.f;
    #pragma unroll
    for(int j=0;j<12;j++){ s+=av[j]; ss+=av[j]*av[j]; }
    #pragma unroll
    for(int o=1;o<8;o<<=1){ s+=__shfl_xor(s,o); ss+=__shfl_xor(ss,o); }
    float m=s*(1.f/96.f), var=ss*(1.f/96.f)-m*m, rstd=rsqrtf(var+EPS);
    // gated instance-normalized cnn half: compute BEFORE overwriting (pj is a separate buffer)
    int bv=row_to_bv(r); int b=bv>>15;
    float sg=sig[bv];
    float cv[12];
    #pragma unroll
    for(int j=0;j<12;j++){
        int c=part*12+j;
        float t=sg*pj[(size_t)bv*96+c];
        cv[j]=(t-gMean[b*96+c])*gRstd[b*96+c];
    }
    #pragma unroll
    for(int j=0;j<12;j++){
        int c=part*12+j;
        U[(size_t)r*192+c]=__float2bfloat16((av[j]-m)*rstd*ga[c]+bba[c]);
    }
    #pragma unroll
    for(int j=0;j<12;j++){
        int c=part*12+j;
        U[(size_t)r*192+96+c]=__float2bfloat16(cv[j]);
    }
}

// ---------------- K9b: final 192x192 projection via bf16 MFMA (no LDS, no barriers) ----------------
// C[m][n] = sum_k U[m][k] * WT[n][k]  (gemm_bt convention).
// Frags: A row m=lane&15 of U, B row n=lane&15 of WT, 8 contiguous k at quad*8.
// C/D: col=lane&15 (n), row=quad*4+reg (m).
__global__ __launch_bounds__(256) void k9b_mfma(const __hip_bfloat16* __restrict__ Ubf,
   const __hip_bfloat16* __restrict__ WT, const float* __restrict__ bp,
   float* __restrict__ out)
{
    int tid=threadIdx.x;
    int wave=tid>>6, lane=tid&63;
    int quad=lane>>4, l16=lane&15;
    int rowA = blockIdx.x*64 + wave*16 + l16;
    const short* Us=(const short*)Ubf;
    const short* Ws=(const short*)WT;
    f32x4 acc[12];
    #pragma unroll
    for(int j=0;j<12;j++) acc[j]=(f32x4){0.f,0.f,0.f,0.f};
    #pragma unroll
    for(int t=0;t<6;t++){
        int k0=t*32;
        short8 a = *(const short8*)(Us + (size_t)rowA*192 + k0 + quad*8);
        #pragma unroll
        for(int j=0;j<12;j++){
            short8 bfr = *(const short8*)(Ws + (size_t)(j*16+l16)*192 + k0 + quad*8);
            acc[j]=__builtin_amdgcn_mfma_f32_16x16x32_bf16(a,bfr,acc[j],0,0,0);
        }
    }
    int mbase = blockIdx.x*64 + wave*16 + quad*4;
    #pragma unroll
    for(int j=0;j<12;j++){
        int n=j*16+l16;
        float bias=bp[n];
        #pragma unroll
        for(int r2=0;r2<4;r2++){
            out[(size_t)(mbase+r2)*192 + n] = acc[j][r2] + bias;
        }
    }
}

extern "C" void kernel_launch(void* const* d_in, const int* in_sizes, int n_in,
                              void* d_out, int out_size, void* d_ws, size_t ws_size,
                              hipStream_t stream)
{
    const float* x      =(const float*)d_in[0];
    const float* w_pattn=(const float*)d_in[1];
    const float* b_pattn=(const float*)d_in[2];
    const float* g_aln  =(const float*)d_in[3];
    const float* b_aln  =(const float*)d_in[4];
    const float* w_pcnn =(const float*)d_in[5];
    const float* b_pcnn =(const float*)d_in[6];
    const float* g_cln  =(const float*)d_in[7];
    const float* b_cln  =(const float*)d_in[8];
    const float* dw_w   =(const float*)d_in[9];
    const float* dw_b   =(const float*)d_in[10];
    const float* ci_w1  =(const float*)d_in[11];
    const float* ci_b1  =(const float*)d_in[12];
    const float* ci_w2  =(const float*)d_in[13];
    const float* ci_b2  =(const float*)d_in[14];
    const float* pj_w   =(const float*)d_in[15];
    const float* pj_b   =(const float*)d_in[16];
    const float* qkv_w  =(const float*)d_in[17];
    const float* qkv_b  =(const float*)d_in[18];
    const float* si_w1  =(const float*)d_in[19];
    const float* si_b1  =(const float*)d_in[20];
    const float* si_w2  =(const float*)d_in[21];
    const float* si_b2  =(const float*)d_in[22];
    const float* g_anorm=(const float*)d_in[23];
    const float* b_anorm=(const float*)d_in[24];
    const float* w_proj =(const float*)d_in[25];
    const float* b_proj =(const float*)d_in[26];
    const float* rpb    =(const float*)d_in[27];
    (void)in_sizes; (void)n_in; (void)out_size; (void)ws_size;

    float* ws  =(float*)d_ws;
    float* vol =(float*)d_out;            // volume lives in d_out until k9b_mfma overwrites
    // ws float offsets. NOTE: QKV (bf16) spans float slots [12,582,912, 31,457,280) —
    // anything overlapping that range must be written AFTER k6_attn (QKV death).
    float* XA   = ws;                     // [0, 12,582,912)  -> ATO after k6 -> U (bf16) after k9a2
    float* VOLA = ws + 12582912;          // LN'd cnn volume (dead after k2)
    __hip_bfloat16* QKV = (__hip_bfloat16*)(ws + 12582912);  // overlays dead VOLA after K2
    float* PJ   = ws + 12582912;          // overlays dead QKV after K6
    float* SI12 = ws + 25165824;          // [25,165,824, 26,738,688) (written at k7a, after k6)
    float* SIG  = ws + 26738688;          // [26,738,688, 26,869,760)
    __hip_bfloat16* WT = (__hip_bfloat16*)(ws + 25165824); // overlays SI12 AFTER k7d_sig (18,432 float slots)
    float* Z0   = ws + 31457280;          // zeroed accumulators (3168 floats)
    float* IN_SUM   = Z0;        float* IN_SUMSQ = Z0+768;
    float* POOLED   = Z0+1536;
    float* SI_SUM   = Z0+2304;   float* SI_SUMSQ = Z0+2352;
    float* G_SUM    = Z0+2400;   float* G_SUMSQ  = Z0+2784;
    float* NZ   = ws + 31460448;
    float* IN_MEAN  = NZ;        float* IN_RSTD  = NZ+768;
    float* GATE     = NZ+1536;
    float* SI_MEAN  = NZ+1920;   float* SI_RSTD  = NZ+1968;
    float* G_MEAN   = NZ+2016;   float* G_RSTD   = NZ+2400;

    // 0. split-bf16 weight prep for K1 -> lives in d_out (dead until k2 overwrites it)
    __hip_bfloat16* WT1hi=(__hip_bfloat16*)d_out;            // 55,296 bf16
    __hip_bfloat16* WT1lo=WT1hi+55296;                       // 55,296 bf16 (ends @ 221,184 B)
    kprep1<<<216,256,0,stream>>>(w_pattn,w_pcnn,WT1hi,WT1lo);
    // 1. dual GEMM + LNs via split-bf16 MFMA
    k1_mfma<<<2048,256,0,stream>>>(x,WT1hi,WT1lo,b_pattn,g_aln,b_aln,
                                   b_pcnn,g_cln,b_cln,XA,VOLA);
    // 2. depthwise conv -> d_out (overwrites WT1hi/lo, which are dead after k1)
    k2_dwconv<<<4096,192,0,stream>>>(VOLA,dw_w,dw_b,vol);
    // zero accumulators (VOLA now dead; Z0 sits past QKV's end)
    hipMemsetAsync((void*)Z0, 0, 3168*sizeof(float), stream);
    // 3. instance norm stats + finalize
    k3_stats<<<dim3(128,4),192,0,stream>>>(vol,IN_SUM,IN_SUMSQ);
    k_finalize<<<3,256,0,stream>>>(IN_SUM,IN_SUMSQ,IN_MEAN,IN_RSTD,768,1.f/32768.f);
    // 4. in-place inorm+gelu + pooled ; gate MLP
    k4_apply<<<dim3(128,4),192,0,stream>>>(vol,IN_MEAN,IN_RSTD,POOLED);
    k4b_gate<<<4,128,0,stream>>>(POOLED,ci_w1,ci_b1,ci_w2,ci_b2,GATE);
    // 5. QKV GEMM (bf16 out, gate/scale folded)
    kqkv<<<4096,256,0,stream>>>(XA,qkv_w,qkv_b,GATE,QKV);
    // 6. attention (writes ATO over dead XA)
    k6_attn<<<2048,256,0,stream>>>(QKV,rpb,XA);
    // 7. 1x1 conv 192->96 (PJ overlays dead QKV head)
    k5_pj<<<4096,256,0,stream>>>(vol,pj_w,pj_b,PJ);
    // 8. spatial-interaction path
    k7a_si<<<2048,192,0,stream>>>(XA,si_w1,si_b1,SI12,SI_SUM,SI_SUMSQ);
    k_finalize<<<1,64,0,stream>>>(SI_SUM,SI_SUMSQ,SI_MEAN,SI_RSTD,48,1.f/32768.f);
    k7d_sig<<<512,256,0,stream>>>(SI12,SI_MEAN,SI_RSTD,si_w2,si_b2,SIG);
    // weight transpose/cast for the final MFMA GEMM (overlays SI12, which is now dead)
    kprep<<<144,256,0,stream>>>(w_proj,WT);
    // 9. gated-cnn instance norm stats
    k8_gstats<<<dim3(128,4),192,0,stream>>>(PJ,SIG,G_SUM,G_SUMSQ);
    k_finalize<<<2,256,0,stream>>>(G_SUM,G_SUMSQ,G_MEAN,G_RSTD,384,1.f/32768.f);
    // 10a. LN(attn) + gated inorm -> U bf16, in-place over ATO (ws). d_out untouched.
    k9a2_gather<<<4096,256,0,stream>>>(XA,PJ,SIG,G_MEAN,G_RSTD,g_anorm,b_anorm);
    // 10b. final projection GEMM via MFMA -> d_out (only epilogue stores touch d_out)
    k9b_mfma<<<2048,256,0,stream>>>((const __hip_bfloat16*)XA,WT,b_proj,vol);
}

// Round 3
// 994.995 us; speedup vs baseline: 1.4681x; 1.3052x over previous
//
#include <hip/hip_runtime.h>
#include <hip/hip_bf16.h>
#include <math.h>

#define EPS 1e-5f
#define XAS 97
#define QS 17
#define SS 65

typedef __attribute__((ext_vector_type(8))) short short8;
typedef __attribute__((ext_vector_type(4))) float f32x4;

__device__ __forceinline__ float gelu_f(float x){
    return 0.5f*x*(1.0f+erff(x*0.7071067811865475f));
}
__device__ __forceinline__ float sigmoid_f(float x){
    return 1.0f/(1.0f+__expf(-x));
}
// row (wi*64+n) -> b*32768 + voxel   (window order b,d,h,w ; in-window order wd,wh,ww)
__device__ __forceinline__ int row_to_bv(int r){
    int wi = r >> 6, n = r & 63;
    int b = wi >> 9, rem = wi & 511;
    int zd = rem >> 6, yh = (rem >> 3) & 7, xw = rem & 7;
    int wz = n >> 4, wy = (n >> 2) & 3, wx = n & 3;
    int Dz = (zd<<2)+wz, Hy = (yh<<2)+wy, Wx = (xw<<2)+wx;
    return (b<<15) + (Dz<<10) + (Hy<<5) + Wx;
}
__device__ __forceinline__ int relidx(int i,int j){
    int zi=i>>4, yi=(i>>2)&3, xi=i&3;
    int zj=j>>4, yj=(j>>2)&3, xj=j&3;
    return ((zi-zj+3)*7+(yi-yj+3))*7+(xi-xj+3);
}
// in-register f32x8 -> bf16 hi/lo split
__device__ __forceinline__ void split8(const float* p, short8& hi, short8& lo){
    union{short8 v; __hip_bfloat16 b[8];} uh, ul;
    #pragma unroll
    for(int i=0;i<8;i++){
        float v=p[i];
        __hip_bfloat16 h=__float2bfloat16(v);
        uh.b[i]=h;
        ul.b[i]=__float2bfloat16(v-__bfloat162float(h));
    }
    hi=uh.v; lo=ul.v;
}

// ---------------- Kprep1: combined weight [288][192] -> hi/lo bf16 split ----------------
// WT[n][k] = (n<96 ? w_pattn[k][n] : w_pcnn[k][n-96]) as hi + lo bf16 pair.
__global__ __launch_bounds__(256) void kprep1(const float* __restrict__ w1,
    const float* __restrict__ w2, __hip_bfloat16* __restrict__ WThi,
    __hip_bfloat16* __restrict__ WTlo)
{
    int i=blockIdx.x*256+threadIdx.x;   // 288*192 = 55296 exactly
    int n=i/192, k=i-n*192;
    float v=(n<96)? w1[k*96+n] : w2[k*192+(n-96)];
    __hip_bfloat16 hb=__float2bfloat16(v);
    WThi[i]=hb;
    WTlo[i]=__float2bfloat16(v-__bfloat162float(hb));
}

// ---------------- Kprepq: qkv_w [96][288] -> WTq [288][96] hi/lo bf16 ----------------
__global__ __launch_bounds__(256) void kprepq(const float* __restrict__ w,
    __hip_bfloat16* __restrict__ WThi, __hip_bfloat16* __restrict__ WTlo)
{
    int i=blockIdx.x*256+threadIdx.x;   // 288*96 = 27648 exactly
    int n=i/96, k=i-n*96;
    float v=w[k*288+n];
    __hip_bfloat16 hb=__float2bfloat16(v);
    WThi[i]=hb;
    WTlo[i]=__float2bfloat16(v-__bfloat162float(hb));
}

// ---------------- Kprepp: pj_w [192][96] -> WTp [96][192] hi/lo bf16 ----------------
__global__ __launch_bounds__(256) void kprepp(const float* __restrict__ w,
    __hip_bfloat16* __restrict__ WThi, __hip_bfloat16* __restrict__ WTlo)
{
    int i=blockIdx.x*256+threadIdx.x;   // 96*192 = 18432 exactly
    int n=i/192, k=i-n*192;
    float v=w[k*96+n];
    __hip_bfloat16 hb=__float2bfloat16(v);
    WThi[i]=hb;
    WTlo[i]=__float2bfloat16(v-__bfloat162float(hb));
}

// ============ shared GEMM template notes (k1_mfma / kqkv / k5_pj) ============
// C[m][n] = sum_k A[m][k]*WT[n][k] via 3-term split-bf16 MFMA (fp32-accurate).
// Block = 64 rows, 4 waves (wave w owns rows w*16..w*16+16).
// Per 32-k step: B (all N rows, hi+lo) staged in LDS cooperatively; A loaded
// per-lane from global (row = wave*16+l16, k = t*32+quad*8, 32B) + split in-reg.
// LDS layout: row n = 128B = 8 granules of 16B; logical granule gi (0-3 = hi
// k-slice gi, 4-7 = lo k-slice gi-4) stored at slot = gi ^ (n&7)  ->
// ds_write_b128 and ds_read_b128 both spread 64 lanes evenly over 32 banks.
// Frag read: hi at shorts [n*64 + ((quad^(n&7))<<3)], lo at (^32).

// ---------------- K1: dual GEMM (192->96 & 192->192) + both LayerNorms ----------------
__global__ __launch_bounds__(256,4) void k1_mfma(const float* __restrict__ x,
    const __hip_bfloat16* __restrict__ WThi, const __hip_bfloat16* __restrict__ WTlo,
    const float* __restrict__ b1, const float* __restrict__ g1, const float* __restrict__ bb1,
    const float* __restrict__ b2, const float* __restrict__ g2, const float* __restrict__ bb2,
    float* __restrict__ xa, float* __restrict__ vol)
{
    __shared__ short bs[288*64];          // 36,864 B
    int tid=threadIdx.x;
    int row0=blockIdx.x*64;
    int wave=tid>>6, lane=tid&63, quad=lane>>4, l16=lane&15;
    const short* Whi=(const short*)WThi;
    const short* Wlo=(const short*)WTlo;
    f32x4 acc[18];
    #pragma unroll
    for(int j=0;j<18;j++) acc[j]=(f32x4){0.f,0.f,0.f,0.f};
    const float* aptr = x + (size_t)(row0+wave*16+l16)*192 + quad*8;
    int rbase = l16*64 + ((quad ^ (l16&7))<<3);
    for(int t=0;t<6;t++){
        float av[8];
        *(f32x4*)&av[0]=*(const f32x4*)(aptr + t*32);
        *(f32x4*)&av[4]=*(const f32x4*)(aptr + t*32 + 4);
        if(t) __syncthreads();            // all waves done reading prev step
        #pragma unroll
        for(int it=0;it<9;it++){          // 2304 granules: 288 n x 8 gi
            int u=tid+it*256;
            int n=u>>3, gi=u&7;
            const short* src=(gi<4?Whi:Wlo) + n*192 + t*32 + (gi&3)*8;
            *(short8*)&bs[n*64 + ((gi^(n&7))<<3)] = *(const short8*)src;
        }
        __syncthreads();
        short8 ahi, alo;
        split8(av, ahi, alo);
        #pragma unroll
        for(int j=0;j<18;j++){
            int idx=j*1024+rbase;
            short8 bhi = *(const short8*)&bs[idx];
            short8 blo = *(const short8*)&bs[idx^32];
            acc[j]=__builtin_amdgcn_mfma_f32_16x16x32_bf16(ahi,bhi,acc[j],0,0,0);
            acc[j]=__builtin_amdgcn_mfma_f32_16x16x32_bf16(ahi,blo,acc[j],0,0,0);
            acc[j]=__builtin_amdgcn_mfma_f32_16x16x32_bf16(alo,bhi,acc[j],0,0,0);
        }
    }
    // ---- epilogue: bias + dual LayerNorm, fully in-register ----
    // lane holds rows (wave*16 + quad*4 + reg), col = j*16 + l16
    float bias[18];
    #pragma unroll
    for(int j=0;j<18;j++){ int c=j*16+l16; bias[j]=(c<96)? b1[c] : b2[c-96]; }
    #pragma unroll
    for(int reg=0; reg<4; reg++){
        int grow=row0 + wave*16 + quad*4 + reg;
        // attention half: cols 0..95 (n-tiles 0..5), LN over 96
        float va[6];
        float s=0.f, ss=0.f;
        #pragma unroll
        for(int j=0;j<6;j++){ float v=acc[j][reg]+bias[j]; va[j]=v; s+=v; ss+=v*v; }
        #pragma unroll
        for(int o=1;o<16;o<<=1){ s+=__shfl_xor(s,o); ss+=__shfl_xor(ss,o); }
        float m=s*(1.f/96.f), var=ss*(1.f/96.f)-m*m, rstd=rsqrtf(var+EPS);
        #pragma unroll
        for(int j=0;j<6;j++){
            int c=j*16+l16;
            xa[(size_t)grow*96+c]=(va[j]-m)*rstd*g1[c]+bb1[c];
        }
        // cnn half: cols 96..287 (n-tiles 6..17), LN over 192 -> scatter NDHWC
        float vc[12];
        s=0.f; ss=0.f;
        #pragma unroll
        for(int j=0;j<12;j++){ float v=acc[6+j][reg]+bias[6+j]; vc[j]=v; s+=v; ss+=v*v; }
        #pragma unroll
        for(int o=1;o<16;o<<=1){ s+=__shfl_xor(s,o); ss+=__shfl_xor(ss,o); }
        float m2=s*(1.f/192.f), var2=ss*(1.f/192.f)-m2*m2, rstd2=rsqrtf(var2+EPS);
        int bv=row_to_bv(grow);
        #pragma unroll
        for(int j=0;j<12;j++){
            int c=j*16+l16;
            vol[(size_t)bv*192+c]=(vc[j]-m2)*rstd2*g2[c]+bb2[c];
        }
    }
}

// ---------------- K2: depthwise 3x3x3 conv, NDHWC, slide along W ----------------
__global__ __launch_bounds__(192) void k2_dwconv(const float* __restrict__ vin,
        const float* __restrict__ wd_, const float* __restrict__ bd,
        float* __restrict__ vout)
{
    int c=threadIdx.x;
    int blk=blockIdx.x;
    int Hy=blk&31, Dz=(blk>>5)&31, b=blk>>10;
    float wreg[27];
    #pragma unroll
    for(int t=0;t<27;t++) wreg[t]=wd_[c*27+t];
    float bias=bd[c];
    const float* base=vin + ((size_t)b<<15)*192;
    int voff[9]; bool vld[9];
    #pragma unroll
    for(int i=0;i<9;i++){
        int zz=Dz+i/3-1, yy=Hy+i%3-1;
        vld[i]=(zz>=0&&zz<32&&yy>=0&&yy<32);
        voff[i]=(zz<<10)+(yy<<5);
    }
    float prv[9],cur[9],nxt[9];
    #pragma unroll
    for(int i=0;i<9;i++){
        prv[i]=0.f;
        cur[i]= vld[i]? base[(size_t)(voff[i])*192+c]   : 0.f;
        nxt[i]= vld[i]? base[(size_t)(voff[i]+1)*192+c] : 0.f;
    }
    size_t obase=((size_t)((b<<15)+(Dz<<10)+(Hy<<5)))*192 + c;
    for(int wx=0;wx<32;wx++){
        float o=bias;
        #pragma unroll
        for(int i=0;i<9;i++) o += prv[i]*wreg[i*3] + cur[i]*wreg[i*3+1] + nxt[i]*wreg[i*3+2];
        vout[obase + (size_t)wx*192] = o;
        #pragma unroll
        for(int i=0;i<9;i++){ prv[i]=cur[i]; cur[i]=nxt[i]; }
        int wn=wx+2;
        #pragma unroll
        for(int i=0;i<9;i++) nxt[i]=(vld[i]&&wn<32)? base[(size_t)(voff[i]+wn)*192+c] : 0.f;
    }
}

// ---------------- K3: instance-norm partial sums over spatial (per b,c) ----------------
__global__ __launch_bounds__(192) void k3_stats(const float* __restrict__ v,
      float* __restrict__ sum, float* __restrict__ sumsq)
{
    int c=threadIdx.x;
    int chunk=blockIdx.x, b=blockIdx.y;
    float s=0.f,ss=0.f;
    const float* p = v + (((size_t)b<<15) + (size_t)chunk*256)*192 + c;
    for(int i=0;i<256;i++){ float t=p[(size_t)i*192]; s+=t; ss+=t*t; }
    atomicAdd(&sum[b*192+c], s);
    atomicAdd(&sumsq[b*192+c], ss);
}

__global__ void k_finalize(const float* __restrict__ sum, const float* __restrict__ sumsq,
                           float* __restrict__ mean, float* __restrict__ rstd, int n, float inv)
{
    int i = blockIdx.x*blockDim.x + threadIdx.x;
    if(i<n){ float m=sum[i]*inv; float v=sumsq[i]*inv - m*m; mean[i]=m; rstd[i]=rsqrtf(v+EPS); }
}

// ---------------- K4: in-place inorm+gelu + pooled partials ----------------
__global__ __launch_bounds__(192) void k4_apply(float* __restrict__ v,
      const float* __restrict__ mean, const float* __restrict__ rstd, float* __restrict__ pooled)
{
    int c=threadIdx.x; int chunk=blockIdx.x, b=blockIdx.y;
    float m=mean[b*192+c], r=rstd[b*192+c];
    float s=0.f;
    float* p = v + (((size_t)b<<15)+(size_t)chunk*256)*192 + c;
    for(int i=0;i<256;i++){
        float t=(p[(size_t)i*192]-m)*r;
        t=gelu_f(t);
        p[(size_t)i*192]=t; s+=t;
    }
    atomicAdd(&pooled[b*192+c], s);
}

// ---------------- K4b: channel-interaction MLP -> sigmoid gate ----------------
__global__ __launch_bounds__(128) void k4b_gate(const float* __restrict__ pooled,
   const float* __restrict__ w1,const float* __restrict__ b1,
   const float* __restrict__ w2,const float* __restrict__ b2, float* __restrict__ gate)
{
    __shared__ float pm[192];
    __shared__ float h[24];
    int b=blockIdx.x, t=threadIdx.x;
    for(int i=t;i<192;i+=128) pm[i]=pooled[b*192+i]*(1.f/32768.f);
    __syncthreads();
    if(t<24){ float a=b1[t]; for(int k=0;k<192;k++) a+=pm[k]*w1[k*24+t]; h[t]=gelu_f(a); }
    __syncthreads();
    if(t<96){ float a=b2[t]; for(int j=0;j<24;j++) a+=h[j]*w2[j*96+t]; gate[b*96+t]=sigmoid_f(a); }
}

// ---------------- Kqkv: QKV GEMM (K=96) via split-bf16 MFMA, q*0.25 / v*gate folded ------
__global__ __launch_bounds__(256,4) void kqkv(const float* __restrict__ xa,
    const __hip_bfloat16* __restrict__ WThi, const __hip_bfloat16* __restrict__ WTlo,
    const float* __restrict__ bias_, const float* __restrict__ gate,
    __hip_bfloat16* __restrict__ qkv)
{
    __shared__ short bs[288*64];
    int tid=threadIdx.x;
    int row0=blockIdx.x*64;
    int wave=tid>>6, lane=tid&63, quad=lane>>4, l16=lane&15;
    const short* Whi=(const short*)WThi;
    const short* Wlo=(const short*)WTlo;
    f32x4 acc[18];
    #pragma unroll
    for(int j=0;j<18;j++) acc[j]=(f32x4){0.f,0.f,0.f,0.f};
    const float* aptr = xa + (size_t)(row0+wave*16+l16)*96 + quad*8;
    int rbase = l16*64 + ((quad ^ (l16&7))<<3);
    for(int t=0;t<3;t++){
        float av[8];
        *(f32x4*)&av[0]=*(const f32x4*)(aptr + t*32);
        *(f32x4*)&av[4]=*(const f32x4*)(aptr + t*32 + 4);
        if(t) __syncthreads();
        #pragma unroll
        for(int it=0;it<9;it++){
            int u=tid+it*256;
            int n=u>>3, gi=u&7;
            const short* src=(gi<4?Whi:Wlo) + n*96 + t*32 + (gi&3)*8;
            *(short8*)&bs[n*64 + ((gi^(n&7))<<3)] = *(const short8*)src;
        }
        __syncthreads();
        short8 ahi, alo;
        split8(av, ahi, alo);
        #pragma unroll
        for(int j=0;j<18;j++){
            int idx=j*1024+rbase;
            short8 bhi = *(const short8*)&bs[idx];
            short8 blo = *(const short8*)&bs[idx^32];
            acc[j]=__builtin_amdgcn_mfma_f32_16x16x32_bf16(ahi,bhi,acc[j],0,0,0);
            acc[j]=__builtin_amdgcn_mfma_f32_16x16x32_bf16(ahi,blo,acc[j],0,0,0);
            acc[j]=__builtin_amdgcn_mfma_f32_16x16x32_bf16(alo,bhi,acc[j],0,0,0);
        }
    }
    // epilogue: col = j*16+l16, slab = wi*18 + j (which*6+hh == j), e = l16
    int b = row0>>15;                   // block rows never straddle a batch (64 | 32768)
    float gv[6];
    #pragma unroll
    for(int j=0;j<6;j++) gv[j]=gate[b*96 + j*16 + l16];
    #pragma unroll
    for(int j=0;j<18;j++){
        float bb=bias_[j*16+l16];
        int which=j/6;
        #pragma unroll
        for(int reg=0;reg<4;reg++){
            int row=row0+wave*16+quad*4+reg;
            int wi=row>>6, n=row&63;
            float v=acc[j][reg]+bb;
            if(which==0) v*=0.25f;
            else if(which==2) v*=gv[j-12];
            qkv[((size_t)(wi*18+j)<<10) + (n<<4) + l16]=__float2bfloat16(v);
        }
    }
}

// ---------------- K6: windowed attention (per window, loop heads) ----------------
__global__ __launch_bounds__(256) void k6_attn(const __hip_bfloat16* __restrict__ qkv,
    const float* __restrict__ rpb, float* __restrict__ ato)
{
    __shared__ float sq[64*QS], sk[64*QS], sv[64*QS];
    __shared__ float sS[64*SS];
    int tid=threadIdx.x;
    int wi=blockIdx.x;
    for(int h=0;h<6;h++){
        __syncthreads();
        for(int i=tid;i<3*1024;i+=256){
            int which=i>>10, r=i&1023; int n=r>>4, e=r&15;
            float val=__bfloat162float(qkv[((size_t)(wi*18+which*6+h)<<10) + r]);
            if(which==0) sq[n*QS+e]=val; else if(which==1) sk[n*QS+e]=val; else sv[n*QS+e]=val;
        }
        __syncthreads();
        {   // S = qk^T + bias : 4x4 tiles
            int ti=tid>>4, tj=tid&15;
            int i0=ti*4, j0=tj*4;
            float a[4][4]={};
            #pragma unroll
            for(int e=0;e<16;e++){
                float qv[4], kv[4];
                #pragma unroll
                for(int ii=0;ii<4;ii++) qv[ii]=sq[(i0+ii)*QS+e];
                #pragma unroll
                for(int jj=0;jj<4;jj++) kv[jj]=sk[(j0+jj)*QS+e];
                #pragma unroll
                for(int ii=0;ii<4;ii++)
                    #pragma unroll
                    for(int jj=0;jj<4;jj++) a[ii][jj]+=qv[ii]*kv[jj];
            }
            #pragma unroll
            for(int ii=0;ii<4;ii++)
                #pragma unroll
                for(int jj=0;jj<4;jj++)
                    sS[(i0+ii)*SS+j0+jj]=a[ii][jj]+rpb[relidx(i0+ii,j0+jj)*6+h];
        }
        __syncthreads();
        {   // softmax rows (4 lanes per row)
            int i=tid>>2, j0=(tid&3)<<4;
            float mx=-1e30f;
            for(int jj=0;jj<16;jj++) mx=fmaxf(mx,sS[i*SS+j0+jj]);
            for(int o=1;o<4;o<<=1) mx=fmaxf(mx,__shfl_xor(mx,o));
            float sum=0.f;
            for(int jj=0;jj<16;jj++){float p=__expf(sS[i*SS+j0+jj]-mx); sS[i*SS+j0+jj]=p; sum+=p;}
            for(int o=1;o<4;o<<=1) sum+=__shfl_xor(sum,o);
            float inv=1.f/sum;
            for(int jj=0;jj<16;jj++) sS[i*SS+j0+jj]*=inv;
        }
        __syncthreads();
        {   // O = P @ v
            int i=tid&63, e0=(tid>>6)<<2;
            float o0=0.f,o1=0.f,o2=0.f,o3=0.f;
            for(int j=0;j<64;j++){
                float p=sS[i*SS+j];
                o0+=p*sv[j*QS+e0];o1+=p*sv[j*QS+e0+1];o2+=p*sv[j*QS+e0+2];o3+=p*sv[j*QS+e0+3];
            }
            float* dst=&ato[((size_t)(wi*64+i))*96 + (h<<4) + e0];
            dst[0]=o0;dst[1]=o1;dst[2]=o2;dst[3]=o3;
        }
    }
}

// ---------------- K5: 1x1 conv 192->96 via split-bf16 MFMA ----------------
__global__ __launch_bounds__(256) void k5_pj(const float* __restrict__ vin,
    const __hip_bfloat16* __restrict__ WThi, const __hip_bfloat16* __restrict__ WTlo,
    const float* __restrict__ bias_, float* __restrict__ out)
{
    __shared__ short bs[96*64];           // 12,288 B
    int tid=threadIdx.x;
    int row0=blockIdx.x*64;
    int wave=tid>>6, lane=tid&63, quad=lane>>4, l16=lane&15;
    const short* Whi=(const short*)WThi;
    const short* Wlo=(const short*)WTlo;
    f32x4 acc[6];
    #pragma unroll
    for(int j=0;j<6;j++) acc[j]=(f32x4){0.f,0.f,0.f,0.f};
    const float* aptr = vin + (size_t)(row0+wave*16+l16)*192 + quad*8;
    int rbase = l16*64 + ((quad ^ (l16&7))<<3);
    for(int t=0;t<6;t++){
        float av[8];
        *(f32x4*)&av[0]=*(const f32x4*)(aptr + t*32);
        *(f32x4*)&av[4]=*(const f32x4*)(aptr + t*32 + 4);
        if(t) __syncthreads();
        #pragma unroll
        for(int it=0;it<3;it++){          // 768 granules: 96 n x 8 gi
            int u=tid+it*256;
            int n=u>>3, gi=u&7;
            const short* src=(gi<4?Whi:Wlo) + n*192 + t*32 + (gi&3)*8;
            *(short8*)&bs[n*64 + ((gi^(n&7))<<3)] = *(const short8*)src;
        }
        __syncthreads();
        short8 ahi, alo;
        split8(av, ahi, alo);
        #pragma unroll
        for(int j=0;j<6;j++){
            int idx=j*1024+rbase;
            short8 bhi = *(const short8*)&bs[idx];
            short8 blo = *(const short8*)&bs[idx^32];
            acc[j]=__builtin_amdgcn_mfma_f32_16x16x32_bf16(ahi,bhi,acc[j],0,0,0);
            acc[j]=__builtin_amdgcn_mfma_f32_16x16x32_bf16(ahi,blo,acc[j],0,0,0);
            acc[j]=__builtin_amdgcn_mfma_f32_16x16x32_bf16(alo,bhi,acc[j],0,0,0);
        }
    }
    #pragma unroll
    for(int j=0;j<6;j++){
        int cc=j*16+l16;
        float bb=bias_[cc];
        #pragma unroll
        for(int reg=0;reg<4;reg++){
            int row=row0+wave*16+quad*4+reg;
            out[(size_t)row*96+cc]=acc[j][reg]+bb;
        }
    }
}

// ---------------- K7a: spatial-interaction conv1 (96->12) + stats ----------------
__global__ __launch_bounds__(192) void k7a_si(const float* __restrict__ ato,
    const float* __restrict__ w1, const float* __restrict__ b1,
    float* __restrict__ si12, float* __restrict__ siSum, float* __restrict__ siSumsq)
{
    __shared__ float sa[64*XAS];
    __shared__ float sw[96*12];
    __shared__ float red[24];
    int tid=threadIdx.x, wi=blockIdx.x, b=wi>>9;
    for(int i=tid;i<64*96;i+=192){ int n=i/96,c=i-n*96; sa[n*XAS+c]=ato[((size_t)(wi*64+n))*96+c]; }
    for(int i=tid;i<96*12;i+=192) sw[i]=w1[i];
    if(tid<24) red[tid]=0.f;
    __syncthreads();
    #pragma unroll
    for(int j=0;j<4;j++){
        int o=tid+192*j; int n=o/12, cc=o-n*12;
        float a=b1[cc];
        for(int k=0;k<96;k++) a+=sa[n*XAS+k]*sw[k*12+cc];
        atomicAdd(&red[cc],a);
        atomicAdd(&red[12+cc],a*a);
        int bv=row_to_bv(wi*64+n);
        si12[(size_t)bv*12+cc]=a;
    }
    __syncthreads();
    if(tid<12){ atomicAdd(&siSum[b*12+tid],red[tid]); atomicAdd(&siSumsq[b*12+tid],red[12+tid]); }
}

// ---------------- K7d: inorm+gelu on si12, conv2 (12->1), sigmoid ----------------
__global__ __launch_bounds__(256) void k7d_sig(const float* __restrict__ si12,
  const float* __restrict__ mean, const float* __restrict__ rstd,
  const float* __restrict__ w2, const float* __restrict__ b2, float* __restrict__ sig)
{
    int bv=blockIdx.x*256+threadIdx.x;
    int b=bv>>15;
    float a=b2[0];
    #pragma unroll
    for(int c=0;c<12;c++){
        float t=(si12[(size_t)bv*12+c]-mean[b*12+c])*rstd[b*12+c];
        a+=gelu_f(t)*w2[c];
    }
    sig[bv]=sigmoid_f(a);
}

// ---------------- K8: stats of sigmoid(si)*PJ (per b,c of 96) ----------------
__global__ __launch_bounds__(192) void k8_gstats(const float* __restrict__ pj,
   const float* __restrict__ sig, float* __restrict__ gSum, float* __restrict__ gSumsq)
{
    int tid=threadIdx.x; int c=tid%96, vh=tid/96;
    int chunk=blockIdx.x, b=blockIdx.y;
    float s=0.f,ss=0.f;
    for(int i=0;i<128;i++){
        int v=chunk*256 + i*2 + vh;
        int bv=(b<<15)+v;
        float t=sig[bv]*pj[(size_t)bv*96+c];
        s+=t; ss+=t*t;
    }
    atomicAdd(&gSum[b*96+c],s); atomicAdd(&gSumsq[b*96+c],ss);
}

// ---------------- Kprep: w_proj (192x192 f32, [k][n]) -> WT bf16 [n][k] ----------------
__global__ __launch_bounds__(256) void kprep(const float* __restrict__ wp,
                                             __hip_bfloat16* __restrict__ WT)
{
    int i=blockIdx.x*256+threadIdx.x;     // 36864 total
    int n=i/192, k=i-n*192;
    WT[n*192+k]=__float2bfloat16(wp[k*192+n]);
}

// ---------------- K9a2: LN(attn) + gated-inorm -> U (bf16, in-place over ATO) ----------------
// Row r: reads ato[r*96 .. r*96+96) (f32, 384B) and writes U row r as 192 bf16 over the
// SAME 384 bytes. The 8 lanes owning a row are in one wave; all f32 loads are issued
// before any bf16 store in program order -> wave-lockstep safe.
__global__ __launch_bounds__(256) void k9a2_gather(float* atoU,
  const float* __restrict__ pj, const float* __restrict__ sig,
  const float* __restrict__ gMean, const float* __restrict__ gRstd,
  const float* __restrict__ ga, const float* __restrict__ bba)
{
    int tid=threadIdx.x; int row0=blockIdx.x*32;
    int rr=tid>>3, part=tid&7;
    int r=row0+rr;
    __hip_bfloat16* U=(__hip_bfloat16*)atoU;
    float av[12];
    #pragma unroll
    for(int j=0;j<12;j++) av[j]=atoU[(size_t)r*96+part*12+j];
    float s=0.f, ss=0.f;
    #pragma unroll
    for(int j=0;j<12;j++){ s+=av[j]; ss+=av[j]*av[j]; }
    #pragma unroll
    for(int o=1;o<8;o<<=1){ s+=__shfl_xor(s,o); ss+=__shfl_xor(ss,o); }
    float m=s*(1.f/96.f), var=ss*(1.f/96.f)-m*m, rstd=rsqrtf(var+EPS);
    // gated instance-normalized cnn half: compute BEFORE overwriting (pj is a separate buffer)
    int bv=row_to_bv(r); int b=bv>>15;
    float sg=sig[bv];
    float cv[12];
    #pragma unroll
    for(int j=0;j<12;j++){
        int c=part*12+j;
        float t=sg*pj[(size_t)bv*96+c];
        cv[j]=(t-gMean[b*96+c])*gRstd[b*96+c];
    }
    #pragma unroll
    for(int j=0;j<12;j++){
        int c=part*12+j;
        U[(size_t)r*192+c]=__float2bfloat16((av[j]-m)*rstd*ga[c]+bba[c]);
    }
    #pragma unroll
    for(int j=0;j<12;j++){
        int c=part*12+j;
        U[(size_t)r*192+96+c]=__float2bfloat16(cv[j]);
    }
}

// ---------------- K9b: final 192x192 projection via bf16 MFMA (no LDS, no barriers) ----------------
// C[m][n] = sum_k U[m][k] * WT[n][k]  (gemm_bt convention).
// Frags: A row m=lane&15 of U, B row n=lane&15 of WT, 8 contiguous k at quad*8.
// C/D: col=lane&15 (n), row=quad*4+reg (m).
__global__ __launch_bounds__(256) void k9b_mfma(const __hip_bfloat16* __restrict__ Ubf,
   const __hip_bfloat16* __restrict__ WT, const float* __restrict__ bp,
   float* __restrict__ out)
{
    int tid=threadIdx.x;
    int wave=tid>>6, lane=tid&63;
    int quad=lane>>4, l16=lane&15;
    int rowA = blockIdx.x*64 + wave*16 + l16;
    const short* Us=(const short*)Ubf;
    const short* Ws=(const short*)WT;
    f32x4 acc[12];
    #pragma unroll
    for(int j=0;j<12;j++) acc[j]=(f32x4){0.f,0.f,0.f,0.f};
    #pragma unroll
    for(int t=0;t<6;t++){
        int k0=t*32;
        short8 a = *(const short8*)(Us + (size_t)rowA*192 + k0 + quad*8);
        #pragma unroll
        for(int j=0;j<12;j++){
            short8 bfr = *(const short8*)(Ws + (size_t)(j*16+l16)*192 + k0 + quad*8);
            acc[j]=__builtin_amdgcn_mfma_f32_16x16x32_bf16(a,bfr,acc[j],0,0,0);
        }
    }
    int mbase = blockIdx.x*64 + wave*16 + quad*4;
    #pragma unroll
    for(int j=0;j<12;j++){
        int n=j*16+l16;
        float bias=bp[n];
        #pragma unroll
        for(int r2=0;r2<4;r2++){
            out[(size_t)(mbase+r2)*192 + n] = acc[j][r2] + bias;
        }
    }
}

extern "C" void kernel_launch(void* const* d_in, const int* in_sizes, int n_in,
                              void* d_out, int out_size, void* d_ws, size_t ws_size,
                              hipStream_t stream)
{
    const float* x      =(const float*)d_in[0];
    const float* w_pattn=(const float*)d_in[1];
    const float* b_pattn=(const float*)d_in[2];
    const float* g_aln  =(const float*)d_in[3];
    const float* b_aln  =(const float*)d_in[4];
    const float* w_pcnn =(const float*)d_in[5];
    const float* b_pcnn =(const float*)d_in[6];
    const float* g_cln  =(const float*)d_in[7];
    const float* b_cln  =(const float*)d_in[8];
    const float* dw_w   =(const float*)d_in[9];
    const float* dw_b   =(const float*)d_in[10];
    const float* ci_w1  =(const float*)d_in[11];
    const float* ci_b1  =(const float*)d_in[12];
    const float* ci_w2  =(const float*)d_in[13];
    const float* ci_b2  =(const float*)d_in[14];
    const float* pj_w   =(const float*)d_in[15];
    const float* pj_b   =(const float*)d_in[16];
    const float* qkv_w  =(const float*)d_in[17];
    const float* qkv_b  =(const float*)d_in[18];
    const float* si_w1  =(const float*)d_in[19];
    const float* si_b1  =(const float*)d_in[20];
    const float* si_w2  =(const float*)d_in[21];
    const float* si_b2  =(const float*)d_in[22];
    const float* g_anorm=(const float*)d_in[23];
    const float* b_anorm=(const float*)d_in[24];
    const float* w_proj =(const float*)d_in[25];
    const float* b_proj =(const float*)d_in[26];
    const float* rpb    =(const float*)d_in[27];
    (void)in_sizes; (void)n_in; (void)out_size; (void)ws_size;

    float* ws  =(float*)d_ws;
    float* vol =(float*)d_out;            // volume lives in d_out until k9b_mfma overwrites
    // ws float offsets. NOTE: VOLA spans [12,582,912, 37,748,736) while live (k1->k2);
    // QKV (bf16) spans float slots [12,582,912, 31,457,280) while live (kqkv->k6).
    // Anything inside VOLA's span may be written ONLY after k2; anything inside QKV's
    // span only after k6 (except Z0/NZ/WTQ, which sit past QKV's end).
    float* XA   = ws;                     // [0, 12,582,912)  -> ATO after k6 -> U (bf16) after k9a2
    float* VOLA = ws + 12582912;          // LN'd cnn volume (dead after k2)
    __hip_bfloat16* QKV = (__hip_bfloat16*)(ws + 12582912);  // overlays dead VOLA after K2
    float* PJ   = ws + 12582912;          // overlays dead QKV after K6
    float* SI12 = ws + 25165824;          // [25,165,824, 26,738,688) (written at k7a, after k6)
    float* SIG  = ws + 26738688;          // [26,738,688, 26,869,760)
    __hip_bfloat16* WT = (__hip_bfloat16*)(ws + 25165824); // overlays SI12 AFTER k7d_sig (18,432 float slots)
    // WTp (pj weights hi/lo, 18,432 floats) in the post-k6 dead zone right after SIG:
    // [26,869,760, 26,888,192) — inside dead-QKV span, written by kprepp AFTER k6_attn.
    __hip_bfloat16* WTPHI = (__hip_bfloat16*)(ws + 26869760);
    __hip_bfloat16* WTPLO = WTPHI + 18432;
    float* Z0   = ws + 31457280;          // zeroed accumulators (3168 floats)
    float* IN_SUM   = Z0;        float* IN_SUMSQ = Z0+768;
    float* POOLED   = Z0+1536;
    float* SI_SUM   = Z0+2304;   float* SI_SUMSQ = Z0+2352;
    float* G_SUM    = Z0+2400;   float* G_SUMSQ  = Z0+2784;
    float* NZ   = ws + 31460448;
    float* IN_MEAN  = NZ;        float* IN_RSTD  = NZ+768;
    float* GATE     = NZ+1536;
    float* SI_MEAN  = NZ+1920;   float* SI_RSTD  = NZ+1968;
    float* G_MEAN   = NZ+2016;   float* G_RSTD   = NZ+2400;
    // qkv weights hi/lo (27,648 floats): [31,463,248, 31,490,896). Past QKV's end and
    // past Z0/NZ, but INSIDE VOLA's span -> must be written AFTER k2 (VOLA death).
    __hip_bfloat16* WTQHI = (__hip_bfloat16*)(ws + 31463248);
    __hip_bfloat16* WTQLO = WTQHI + 27648;

    // 0. weight prep for K1 -> d_out (dead until k2)
    __hip_bfloat16* WT1hi=(__hip_bfloat16*)d_out;            // 55,296 bf16
    __hip_bfloat16* WT1lo=WT1hi+55296;                       // 55,296 bf16 (ends @ 221,184 B)
    kprep1<<<216,256,0,stream>>>(w_pattn,w_pcnn,WT1hi,WT1lo);
    // 1. dual GEMM + LNs via split-bf16 MFMA (LDS-staged B, reg-A)
    k1_mfma<<<2048,256,0,stream>>>(x,WT1hi,WT1lo,b_pattn,g_aln,b_aln,
                                   b_pcnn,g_cln,b_cln,XA,VOLA);
    // 2. depthwise conv -> d_out (overwrites WT1hi/lo, which are dead after k1)
    k2_dwconv<<<4096,192,0,stream>>>(VOLA,dw_w,dw_b,vol);
    // zero accumulators + qkv weight prep (both regions inside VOLA span -> only
    // safe to write now, after k2. Previous round wrote WTQ BEFORE k1 -> k1's VOLA
    // stores clobbered it -> NaN. Order fixed here.)
    hipMemsetAsync((void*)Z0, 0, 3168*sizeof(float), stream);
    kprepq<<<108,256,0,stream>>>(qkv_w,WTQHI,WTQLO);
    // 3. instance norm stats + finalize
    k3_stats<<<dim3(128,4),192,0,stream>>>(vol,IN_SUM,IN_SUMSQ);
    k_finalize<<<3,256,0,stream>>>(IN_SUM,IN_SUMSQ,IN_MEAN,IN_RSTD,768,1.f/32768.f);
    // 4. in-place inorm+gelu + pooled ; gate MLP
    k4_apply<<<dim3(128,4),192,0,stream>>>(vol,IN_MEAN,IN_RSTD,POOLED);
    k4b_gate<<<4,128,0,stream>>>(POOLED,ci_w1,ci_b1,ci_w2,ci_b2,GATE);
    // 5. QKV GEMM via split-bf16 MFMA (bf16 out, gate/scale folded)
    kqkv<<<2048,256,0,stream>>>(XA,WTQHI,WTQLO,qkv_b,GATE,QKV);
    // 6. attention (writes ATO over dead XA)
    k6_attn<<<2048,256,0,stream>>>(QKV,rpb,XA);
    // 7. pj weight prep (region is dead-QKV, safe only after k6), then 1x1 conv 192->96
    kprepp<<<72,256,0,stream>>>(pj_w,WTPHI,WTPLO);
    k5_pj<<<2048,256,0,stream>>>(vol,WTPHI,WTPLO,pj_b,PJ);
    // 8. spatial-interaction path
    k7a_si<<<2048,192,0,stream>>>(XA,si_w1,si_b1,SI12,SI_SUM,SI_SUMSQ);
    k_finalize<<<1,64,0,stream>>>(SI_SUM,SI_SUMSQ,SI_MEAN,SI_RSTD,48,1.f/32768.f);
    k7d_sig<<<512,256,0,stream>>>(SI12,SI_MEAN,SI_RSTD,si_w2,si_b2,SIG);
    // weight transpose/cast for the final MFMA GEMM (overlays SI12, which is now dead)
    kprep<<<144,256,0,stream>>>(w_proj,WT);
    // 9. gated-cnn instance norm stats
    k8_gstats<<<dim3(128,4),192,0,stream>>>(PJ,SIG,G_SUM,G_SUMSQ);
    k_finalize<<<2,256,0,stream>>>(G_SUM,G_SUMSQ,G_MEAN,G_RSTD,384,1.f/32768.f);
    // 10a. LN(attn) + gated inorm -> U bf16, in-place over ATO (ws). d_out untouched.
    k9a2_gather<<<4096,256,0,stream>>>(XA,PJ,SIG,G_MEAN,G_RSTD,g_anorm,b_anorm);
    // 10b. final projection GEMM via MFMA -> d_out (only epilogue stores touch d_out)
    k9b_mfma<<<2048,256,0,stream>>>((const __hip_bfloat16*)XA,WT,b_proj,vol);
}

// Round 4
// 843.551 us; speedup vs baseline: 1.7316x; 1.1795x over previous
//
#include <hip/hip_runtime.h>
#include <hip/hip_bf16.h>
#include <math.h>

#define EPS 1e-5f
#define XAS 97

typedef __attribute__((ext_vector_type(8))) short short8;
typedef __attribute__((ext_vector_type(4))) float f32x4;

__device__ __forceinline__ float gelu_f(float x){
    return 0.5f*x*(1.0f+erff(x*0.7071067811865475f));
}
__device__ __forceinline__ float sigmoid_f(float x){
    return 1.0f/(1.0f+__expf(-x));
}
__device__ __forceinline__ short bf16s(float x){
    __hip_bfloat16 h=__float2bfloat16(x);
    return *(short*)&h;
}
// row (wi*64+n) -> b*32768 + voxel   (window order b,d,h,w ; in-window order wd,wh,ww)
__device__ __forceinline__ int row_to_bv(int r){
    int wi = r >> 6, n = r & 63;
    int b = wi >> 9, rem = wi & 511;
    int zd = rem >> 6, yh = (rem >> 3) & 7, xw = rem & 7;
    int wz = n >> 4, wy = (n >> 2) & 3, wx = n & 3;
    int Dz = (zd<<2)+wz, Hy = (yh<<2)+wy, Wx = (xw<<2)+wx;
    return (b<<15) + (Dz<<10) + (Hy<<5) + Wx;
}
__device__ __forceinline__ int relidx(int i,int j){
    int zi=i>>4, yi=(i>>2)&3, xi=i&3;
    int zj=j>>4, yj=(j>>2)&3, xj=j&3;
    return ((zi-zj+3)*7+(yi-yj+3))*7+(xi-xj+3);
}
// in-register f32x8 -> bf16 hi/lo split
__device__ __forceinline__ void split8(const float* p, short8& hi, short8& lo){
    union{short8 v; __hip_bfloat16 b[8];} uh, ul;
    #pragma unroll
    for(int i=0;i<8;i++){
        float v=p[i];
        __hip_bfloat16 h=__float2bfloat16(v);
        uh.b[i]=h;
        ul.b[i]=__float2bfloat16(v-__bfloat162float(h));
    }
    hi=uh.v; lo=ul.v;
}

// ---------------- Kprep1: combined weight [288][192] -> hi/lo bf16 split ----------------
// WT[n][k] = (n<96 ? w_pattn[k][n] : w_pcnn[k][n-96]) as hi + lo bf16 pair.
__global__ __launch_bounds__(256) void kprep1(const float* __restrict__ w1,
    const float* __restrict__ w2, __hip_bfloat16* __restrict__ WThi,
    __hip_bfloat16* __restrict__ WTlo)
{
    int i=blockIdx.x*256+threadIdx.x;   // 288*192 = 55296 exactly
    int n=i/192, k=i-n*192;
    float v=(n<96)? w1[k*96+n] : w2[k*192+(n-96)];
    __hip_bfloat16 hb=__float2bfloat16(v);
    WThi[i]=hb;
    WTlo[i]=__float2bfloat16(v-__bfloat162float(hb));
}

// ---------------- Kprepq: qkv_w [96][288] -> WTq [288][96] hi/lo bf16 ----------------
__global__ __launch_bounds__(256) void kprepq(const float* __restrict__ w,
    __hip_bfloat16* __restrict__ WThi, __hip_bfloat16* __restrict__ WTlo)
{
    int i=blockIdx.x*256+threadIdx.x;   // 288*96 = 27648 exactly
    int n=i/96, k=i-n*96;
    float v=w[k*288+n];
    __hip_bfloat16 hb=__float2bfloat16(v);
    WThi[i]=hb;
    WTlo[i]=__float2bfloat16(v-__bfloat162float(hb));
}

// ---------------- Kprepp: pj_w [192][96] -> WTp [96][192] hi/lo bf16 ----------------
__global__ __launch_bounds__(256) void kprepp(const float* __restrict__ w,
    __hip_bfloat16* __restrict__ WThi, __hip_bfloat16* __restrict__ WTlo)
{
    int i=blockIdx.x*256+threadIdx.x;   // 96*192 = 18432 exactly
    int n=i/192, k=i-n*192;
    float v=w[k*96+n];
    __hip_bfloat16 hb=__float2bfloat16(v);
    WThi[i]=hb;
    WTlo[i]=__float2bfloat16(v-__bfloat162float(hb));
}

// ============ shared GEMM template notes (k1_mfma / kqkv / k5_pj) ============
// C[m][n] = sum_k A[m][k]*WT[n][k] via 3-term split-bf16 MFMA (fp32-accurate).
// Block = 64 rows, 4 waves (wave w owns rows w*16..w*16+16).
// Per 32-k step: B (all N rows, hi+lo) staged in LDS cooperatively; A loaded
// per-lane from global (row = wave*16+l16, k = t*32+quad*8, 32B) + split in-reg.
// LDS layout: row n = 128B = 8 granules of 16B; logical granule gi (0-3 = hi
// k-slice gi, 4-7 = lo k-slice gi-4) stored at slot = gi ^ (n&7)  ->
// ds_write_b128 and ds_read_b128 both spread 64 lanes evenly over 32 banks.
// Frag read: hi at shorts [n*64 + ((quad^(n&7))<<3)], lo at (^32).

// ---------------- K1: dual GEMM (192->96 & 192->192) + both LayerNorms ----------------
__global__ __launch_bounds__(256,4) void k1_mfma(const float* __restrict__ x,
    const __hip_bfloat16* __restrict__ WThi, const __hip_bfloat16* __restrict__ WTlo,
    const float* __restrict__ b1, const float* __restrict__ g1, const float* __restrict__ bb1,
    const float* __restrict__ b2, const float* __restrict__ g2, const float* __restrict__ bb2,
    float* __restrict__ xa, float* __restrict__ vol)
{
    __shared__ short bs[288*64];          // 36,864 B
    int tid=threadIdx.x;
    int row0=blockIdx.x*64;
    int wave=tid>>6, lane=tid&63, quad=lane>>4, l16=lane&15;
    const short* Whi=(const short*)WThi;
    const short* Wlo=(const short*)WTlo;
    f32x4 acc[18];
    #pragma unroll
    for(int j=0;j<18;j++) acc[j]=(f32x4){0.f,0.f,0.f,0.f};
    const float* aptr = x + (size_t)(row0+wave*16+l16)*192 + quad*8;
    int rbase = l16*64 + ((quad ^ (l16&7))<<3);
    for(int t=0;t<6;t++){
        float av[8];
        *(f32x4*)&av[0]=*(const f32x4*)(aptr + t*32);
        *(f32x4*)&av[4]=*(const f32x4*)(aptr + t*32 + 4);
        if(t) __syncthreads();            // all waves done reading prev step
        #pragma unroll
        for(int it=0;it<9;it++){          // 2304 granules: 288 n x 8 gi
            int u=tid+it*256;
            int n=u>>3, gi=u&7;
            const short* src=(gi<4?Whi:Wlo) + n*192 + t*32 + (gi&3)*8;
            *(short8*)&bs[n*64 + ((gi^(n&7))<<3)] = *(const short8*)src;
        }
        __syncthreads();
        short8 ahi, alo;
        split8(av, ahi, alo);
        #pragma unroll
        for(int j=0;j<18;j++){
            int idx=j*1024+rbase;
            short8 bhi = *(const short8*)&bs[idx];
            short8 blo = *(const short8*)&bs[idx^32];
            acc[j]=__builtin_amdgcn_mfma_f32_16x16x32_bf16(ahi,bhi,acc[j],0,0,0);
            acc[j]=__builtin_amdgcn_mfma_f32_16x16x32_bf16(ahi,blo,acc[j],0,0,0);
            acc[j]=__builtin_amdgcn_mfma_f32_16x16x32_bf16(alo,bhi,acc[j],0,0,0);
        }
    }
    // ---- epilogue: bias + dual LayerNorm, fully in-register ----
    // lane holds rows (wave*16 + quad*4 + reg), col = j*16 + l16
    float bias[18];
    #pragma unroll
    for(int j=0;j<18;j++){ int c=j*16+l16; bias[j]=(c<96)? b1[c] : b2[c-96]; }
    #pragma unroll
    for(int reg=0; reg<4; reg++){
        int grow=row0 + wave*16 + quad*4 + reg;
        // attention half: cols 0..95 (n-tiles 0..5), LN over 96
        float va[6];
        float s=0.f, ss=0.f;
        #pragma unroll
        for(int j=0;j<6;j++){ float v=acc[j][reg]+bias[j]; va[j]=v; s+=v; ss+=v*v; }
        #pragma unroll
        for(int o=1;o<16;o<<=1){ s+=__shfl_xor(s,o); ss+=__shfl_xor(ss,o); }
        float m=s*(1.f/96.f), var=ss*(1.f/96.f)-m*m, rstd=rsqrtf(var+EPS);
        #pragma unroll
        for(int j=0;j<6;j++){
            int c=j*16+l16;
            xa[(size_t)grow*96+c]=(va[j]-m)*rstd*g1[c]+bb1[c];
        }
        // cnn half: cols 96..287 (n-tiles 6..17), LN over 192 -> scatter NDHWC
        float vc[12];
        s=0.f; ss=0.f;
        #pragma unroll
        for(int j=0;j<12;j++){ float v=acc[6+j][reg]+bias[6+j]; vc[j]=v; s+=v; ss+=v*v; }
        #pragma unroll
        for(int o=1;o<16;o<<=1){ s+=__shfl_xor(s,o); ss+=__shfl_xor(ss,o); }
        float m2=s*(1.f/192.f), var2=ss*(1.f/192.f)-m2*m2, rstd2=rsqrtf(var2+EPS);
        int bv=row_to_bv(grow);
        #pragma unroll
        for(int j=0;j<12;j++){
            int c=j*16+l16;
            vol[(size_t)bv*192+c]=(vc[j]-m2)*rstd2*g2[c]+bb2[c];
        }
    }
}

// ---------------- K2: depthwise 3x3x3 conv, NDHWC, slide along W ----------------
__global__ __launch_bounds__(192) void k2_dwconv(const float* __restrict__ vin,
        const float* __restrict__ wd_, const float* __restrict__ bd,
        float* __restrict__ vout)
{
    int c=threadIdx.x;
    int blk=blockIdx.x;
    int Hy=blk&31, Dz=(blk>>5)&31, b=blk>>10;
    float wreg[27];
    #pragma unroll
    for(int t=0;t<27;t++) wreg[t]=wd_[c*27+t];
    float bias=bd[c];
    const float* base=vin + ((size_t)b<<15)*192;
    int voff[9]; bool vld[9];
    #pragma unroll
    for(int i=0;i<9;i++){
        int zz=Dz+i/3-1, yy=Hy+i%3-1;
        vld[i]=(zz>=0&&zz<32&&yy>=0&&yy<32);
        voff[i]=(zz<<10)+(yy<<5);
    }
    float prv[9],cur[9],nxt[9];
    #pragma unroll
    for(int i=0;i<9;i++){
        prv[i]=0.f;
        cur[i]= vld[i]? base[(size_t)(voff[i])*192+c]   : 0.f;
        nxt[i]= vld[i]? base[(size_t)(voff[i]+1)*192+c] : 0.f;
    }
    size_t obase=((size_t)((b<<15)+(Dz<<10)+(Hy<<5)))*192 + c;
    for(int wx=0;wx<32;wx++){
        float o=bias;
        #pragma unroll
        for(int i=0;i<9;i++) o += prv[i]*wreg[i*3] + cur[i]*wreg[i*3+1] + nxt[i]*wreg[i*3+2];
        vout[obase + (size_t)wx*192] = o;
        #pragma unroll
        for(int i=0;i<9;i++){ prv[i]=cur[i]; cur[i]=nxt[i]; }
        int wn=wx+2;
        #pragma unroll
        for(int i=0;i<9;i++) nxt[i]=(vld[i]&&wn<32)? base[(size_t)(voff[i]+wn)*192+c] : 0.f;
    }
}

// ---------------- K3: instance-norm partial sums over spatial (per b,c) ----------------
__global__ __launch_bounds__(192) void k3_stats(const float* __restrict__ v,
      float* __restrict__ sum, float* __restrict__ sumsq)
{
    int c=threadIdx.x;
    int chunk=blockIdx.x, b=blockIdx.y;
    float s=0.f,ss=0.f;
    const float* p = v + (((size_t)b<<15) + (size_t)chunk*256)*192 + c;
    for(int i=0;i<256;i++){ float t=p[(size_t)i*192]; s+=t; ss+=t*t; }
    atomicAdd(&sum[b*192+c], s);
    atomicAdd(&sumsq[b*192+c], ss);
}

__global__ void k_finalize(const float* __restrict__ sum, const float* __restrict__ sumsq,
                           float* __restrict__ mean, float* __restrict__ rstd, int n, float inv)
{
    int i = blockIdx.x*blockDim.x + threadIdx.x;
    if(i<n){ float m=sum[i]*inv; float v=sumsq[i]*inv - m*m; mean[i]=m; rstd[i]=rsqrtf(v+EPS); }
}

// ---------------- K4: in-place inorm+gelu + pooled partials ----------------
__global__ __launch_bounds__(192) void k4_apply(float* __restrict__ v,
      const float* __restrict__ mean, const float* __restrict__ rstd, float* __restrict__ pooled)
{
    int c=threadIdx.x; int chunk=blockIdx.x, b=blockIdx.y;
    float m=mean[b*192+c], r=rstd[b*192+c];
    float s=0.f;
    float* p = v + (((size_t)b<<15)+(size_t)chunk*256)*192 + c;
    for(int i=0;i<256;i++){
        float t=(p[(size_t)i*192]-m)*r;
        t=gelu_f(t);
        p[(size_t)i*192]=t; s+=t;
    }
    atomicAdd(&pooled[b*192+c], s);
}

// ---------------- K4b: channel-interaction MLP -> sigmoid gate ----------------
__global__ __launch_bounds__(128) void k4b_gate(const float* __restrict__ pooled,
   const float* __restrict__ w1,const float* __restrict__ b1,
   const float* __restrict__ w2,const float* __restrict__ b2, float* __restrict__ gate)
{
    __shared__ float pm[192];
    __shared__ float h[24];
    int b=blockIdx.x, t=threadIdx.x;
    for(int i=t;i<192;i+=128) pm[i]=pooled[b*192+i]*(1.f/32768.f);
    __syncthreads();
    if(t<24){ float a=b1[t]; for(int k=0;k<192;k++) a+=pm[k]*w1[k*24+t]; h[t]=gelu_f(a); }
    __syncthreads();
    if(t<96){ float a=b2[t]; for(int j=0;j<24;j++) a+=h[j]*w2[j*96+t]; gate[b*96+t]=sigmoid_f(a); }
}

// ---------------- Kqkv: QKV GEMM (K=96) via split-bf16 MFMA, q*0.25 / v*gate folded ------
__global__ __launch_bounds__(256,4) void kqkv(const float* __restrict__ xa,
    const __hip_bfloat16* __restrict__ WThi, const __hip_bfloat16* __restrict__ WTlo,
    const float* __restrict__ bias_, const float* __restrict__ gate,
    __hip_bfloat16* __restrict__ qkv)
{
    __shared__ short bs[288*64];
    int tid=threadIdx.x;
    int row0=blockIdx.x*64;
    int wave=tid>>6, lane=tid&63, quad=lane>>4, l16=lane&15;
    const short* Whi=(const short*)WThi;
    const short* Wlo=(const short*)WTlo;
    f32x4 acc[18];
    #pragma unroll
    for(int j=0;j<18;j++) acc[j]=(f32x4){0.f,0.f,0.f,0.f};
    const float* aptr = xa + (size_t)(row0+wave*16+l16)*96 + quad*8;
    int rbase = l16*64 + ((quad ^ (l16&7))<<3);
    for(int t=0;t<3;t++){
        float av[8];
        *(f32x4*)&av[0]=*(const f32x4*)(aptr + t*32);
        *(f32x4*)&av[4]=*(const f32x4*)(aptr + t*32 + 4);
        if(t) __syncthreads();
        #pragma unroll
        for(int it=0;it<9;it++){
            int u=tid+it*256;
            int n=u>>3, gi=u&7;
            const short* src=(gi<4?Whi:Wlo) + n*96 + t*32 + (gi&3)*8;
            *(short8*)&bs[n*64 + ((gi^(n&7))<<3)] = *(const short8*)src;
        }
        __syncthreads();
        short8 ahi, alo;
        split8(av, ahi, alo);
        #pragma unroll
        for(int j=0;j<18;j++){
            int idx=j*1024+rbase;
            short8 bhi = *(const short8*)&bs[idx];
            short8 blo = *(const short8*)&bs[idx^32];
            acc[j]=__builtin_amdgcn_mfma_f32_16x16x32_bf16(ahi,bhi,acc[j],0,0,0);
            acc[j]=__builtin_amdgcn_mfma_f32_16x16x32_bf16(ahi,blo,acc[j],0,0,0);
            acc[j]=__builtin_amdgcn_mfma_f32_16x16x32_bf16(alo,bhi,acc[j],0,0,0);
        }
    }
    // epilogue: col = j*16+l16, slab = wi*18 + j (which*6+hh == j), e = l16
    int b = row0>>15;                   // block rows never straddle a batch (64 | 32768)
    float gv[6];
    #pragma unroll
    for(int j=0;j<6;j++) gv[j]=gate[b*96 + j*16 + l16];
    #pragma unroll
    for(int j=0;j<18;j++){
        float bb=bias_[j*16+l16];
        int which=j/6;
        #pragma unroll
        for(int reg=0;reg<4;reg++){
            int row=row0+wave*16+quad*4+reg;
            int wi=row>>6, n=row&63;
            float v=acc[j][reg]+bb;
            if(which==0) v*=0.25f;
            else if(which==2) v*=gv[j-12];
            qkv[((size_t)(wi*18+j)<<10) + (n<<4) + l16]=__float2bfloat16(v);
        }
    }
}

// ---------------- K6: windowed attention via MFMA (1 window/block, loop heads) ----------
// Per head: stage Q,K raw bf16 [tok][16] + V transposed [e][tok] (XOR-swizzled).
// S = mfma(Q,K) K=16 padded to 32; wave w owns S rows [16w,16w+16) x 64 cols in regs
// (C layout: row=quad*4+reg, col=jt*16+l16). Softmax in-register (in-lane max over 4
// jt + shfl_xor over the 16-lane quad group). P -> LDS bf16 [q][tok] swizzled (each
// wave touches only its own 16 rows -> same-wave DS ordering, no barrier).
// O^T = mfma(A=V^T rows e, B=P rows q): lane holds O[q=16w+l16][e=quad*4+reg..+3] ->
// one f32x4 store, same ato layout as before.
__global__ __launch_bounds__(256) void k6_attn(const __hip_bfloat16* __restrict__ qkv,
    const float* __restrict__ rpb, float* __restrict__ ato)
{
    __shared__ short qs[1024];     // Q: [tok][16] bf16
    __shared__ short ks_[1024];    // K: [tok][16] bf16
    __shared__ short vt[1024];     // V^T: [e][tok] bf16, row 128B, XOR-swizzled
    __shared__ short ps[4096];     // P: [q][tok] bf16, row 128B, XOR-swizzled
    int tid=threadIdx.x;
    int wi=blockIdx.x;
    int wave=tid>>6, lane=tid&63, quad=lane>>4, l16=lane&15;
    // head-independent relative-position indices for this thread's 16 S elements
    int ridx[4][4];
    #pragma unroll
    for(int jt=0;jt<4;jt++)
        #pragma unroll
        for(int reg=0;reg<4;reg++)
            ridx[jt][reg]=relidx(wave*16+quad*4+reg, jt*16+l16);
    const short* qkvs=(const short*)qkv + ((size_t)(wi*18)<<10);
    int vn=tid>>2, ve0=(tid&3)<<2;
    for(int h=0;h<6;h++){
        __syncthreads();   // prev iteration's LDS consumption complete
        {   // stage Q,K raw (1 b128 per thread) + V transposed (4 b16 per thread)
            const short* src = qkvs + (((tid<128?0:6)+h)<<10) + ((tid&127)<<3);
            short8 v8=*(const short8*)src;
            *(short8*)((tid<128? qs: ks_) + ((tid&127)<<3)) = v8;
            const short* vsrc = qkvs + ((12+h)<<10) + (vn<<4) + ve0;
            #pragma unroll
            for(int j=0;j<4;j++){
                int e=ve0+j;
                vt[(e*64+vn) ^ ((e&7)<<3)] = vsrc[j];
            }
        }
        __syncthreads();
        // S = Q K^T : wave computes rows [wave*16, +16) x all 64 (K=16 padded to 32)
        short8 zf=(short8){0,0,0,0,0,0,0,0};
        short8 afr = (quad<2)? *(const short8*)&qs[(wave*16+l16)*16 + quad*8] : zf;
        f32x4 accs[4];
        #pragma unroll
        for(int jt=0;jt<4;jt++){
            short8 bfr = (quad<2)? *(const short8*)&ks_[(jt*16+l16)*16 + quad*8] : zf;
            accs[jt]=__builtin_amdgcn_mfma_f32_16x16x32_bf16(afr,bfr,(f32x4){0.f,0.f,0.f,0.f},0,0,0);
        }
        // bias + in-register softmax per row (row = wave*16+quad*4+reg), P -> LDS bf16
        #pragma unroll
        for(int reg=0;reg<4;reg++){
            float v0=accs[0][reg]+rpb[ridx[0][reg]*6+h];
            float v1=accs[1][reg]+rpb[ridx[1][reg]*6+h];
            float v2=accs[2][reg]+rpb[ridx[2][reg]*6+h];
            float v3=accs[3][reg]+rpb[ridx[3][reg]*6+h];
            float mx=fmaxf(fmaxf(v0,v1),fmaxf(v2,v3));
            #pragma unroll
            for(int o=1;o<16;o<<=1) mx=fmaxf(mx,__shfl_xor(mx,o));
            float e0=__expf(v0-mx),e1=__expf(v1-mx),e2=__expf(v2-mx),e3=__expf(v3-mx);
            float sm=e0+e1+e2+e3;
            #pragma unroll
            for(int o=1;o<16;o<<=1) sm+=__shfl_xor(sm,o);
            float inv=1.f/sm;
            int i=wave*16+quad*4+reg, ib=(i&7)<<3;
            ps[(i*64 +      l16) ^ ib]=bf16s(e0*inv);
            ps[(i*64 + 16 + l16) ^ ib]=bf16s(e1*inv);
            ps[(i*64 + 32 + l16) ^ ib]=bf16s(e2*inv);
            ps[(i*64 + 48 + l16) ^ ib]=bf16s(e3*inv);
        }
        // same-wave P write->read: DS is in-order per wave; fence against compiler motion
        asm volatile("s_waitcnt lgkmcnt(0)" ::: "memory");
        __builtin_amdgcn_sched_barrier(0);
        // O^T = mfma(A=V^T rows e, B=P rows q=wave*16+l16), K=64 in 2 steps
        f32x4 acco=(f32x4){0.f,0.f,0.f,0.f};
        #pragma unroll
        for(int ks2=0;ks2<2;ks2++){
            short8 a=*(const short8*)&vt[(l16*64 + ks2*32 + quad*8) ^ ((l16&7)<<3)];
            short8 b=*(const short8*)&ps[((wave*16+l16)*64 + ks2*32 + quad*8) ^ ((l16&7)<<3)];
            acco=__builtin_amdgcn_mfma_f32_16x16x32_bf16(a,b,acco,0,0,0);
        }
        // lane holds O[q=wave*16+l16][e=quad*4 .. +3]
        *(f32x4*)&ato[((size_t)(wi*64 + wave*16 + l16))*96 + (h<<4) + quad*4] = acco;
    }
}

// ---------------- K5: 1x1 conv 192->96 via split-bf16 MFMA ----------------
__global__ __launch_bounds__(256) void k5_pj(const float* __restrict__ vin,
    const __hip_bfloat16* __restrict__ WThi, const __hip_bfloat16* __restrict__ WTlo,
    const float* __restrict__ bias_, float* __restrict__ out)
{
    __shared__ short bs[96*64];           // 12,288 B
    int tid=threadIdx.x;
    int row0=blockIdx.x*64;
    int wave=tid>>6, lane=tid&63, quad=lane>>4, l16=lane&15;
    const short* Whi=(const short*)WThi;
    const short* Wlo=(const short*)WTlo;
    f32x4 acc[6];
    #pragma unroll
    for(int j=0;j<6;j++) acc[j]=(f32x4){0.f,0.f,0.f,0.f};
    const float* aptr = vin + (size_t)(row0+wave*16+l16)*192 + quad*8;
    int rbase = l16*64 + ((quad ^ (l16&7))<<3);
    for(int t=0;t<6;t++){
        float av[8];
        *(f32x4*)&av[0]=*(const f32x4*)(aptr + t*32);
        *(f32x4*)&av[4]=*(const f32x4*)(aptr + t*32 + 4);
        if(t) __syncthreads();
        #pragma unroll
        for(int it=0;it<3;it++){          // 768 granules: 96 n x 8 gi
            int u=tid+it*256;
            int n=u>>3, gi=u&7;
            const short* src=(gi<4?Whi:Wlo) + n*192 + t*32 + (gi&3)*8;
            *(short8*)&bs[n*64 + ((gi^(n&7))<<3)] = *(const short8*)src;
        }
        __syncthreads();
        short8 ahi, alo;
        split8(av, ahi, alo);
        #pragma unroll
        for(int j=0;j<6;j++){
            int idx=j*1024+rbase;
            short8 bhi = *(const short8*)&bs[idx];
            short8 blo = *(const short8*)&bs[idx^32];
            acc[j]=__builtin_amdgcn_mfma_f32_16x16x32_bf16(ahi,bhi,acc[j],0,0,0);
            acc[j]=__builtin_amdgcn_mfma_f32_16x16x32_bf16(ahi,blo,acc[j],0,0,0);
            acc[j]=__builtin_amdgcn_mfma_f32_16x16x32_bf16(alo,bhi,acc[j],0,0,0);
        }
    }
    #pragma unroll
    for(int j=0;j<6;j++){
        int cc=j*16+l16;
        float bb=bias_[cc];
        #pragma unroll
        for(int reg=0;reg<4;reg++){
            int row=row0+wave*16+quad*4+reg;
            out[(size_t)row*96+cc]=acc[j][reg]+bb;
        }
    }
}

// ---------------- K7a: spatial-interaction conv1 (96->12) + stats ----------------
__global__ __launch_bounds__(192) void k7a_si(const float* __restrict__ ato,
    const float* __restrict__ w1, const float* __restrict__ b1,
    float* __restrict__ si12, float* __restrict__ siSum, float* __restrict__ siSumsq)
{
    __shared__ float sa[64*XAS];
    __shared__ float sw[96*12];
    __shared__ float red[24];
    int tid=threadIdx.x, wi=blockIdx.x, b=wi>>9;
    for(int i=tid;i<64*96;i+=192){ int n=i/96,c=i-n*96; sa[n*XAS+c]=ato[((size_t)(wi*64+n))*96+c]; }
    for(int i=tid;i<96*12;i+=192) sw[i]=w1[i];
    if(tid<24) red[tid]=0.f;
    __syncthreads();
    #pragma unroll
    for(int j=0;j<4;j++){
        int o=tid+192*j; int n=o/12, cc=o-n*12;
        float a=b1[cc];
        for(int k=0;k<96;k++) a+=sa[n*XAS+k]*sw[k*12+cc];
        atomicAdd(&red[cc],a);
        atomicAdd(&red[12+cc],a*a);
        int bv=row_to_bv(wi*64+n);
        si12[(size_t)bv*12+cc]=a;
    }
    __syncthreads();
    if(tid<12){ atomicAdd(&siSum[b*12+tid],red[tid]); atomicAdd(&siSumsq[b*12+tid],red[12+tid]); }
}

// ---------------- K7d: inorm+gelu on si12, conv2 (12->1), sigmoid ----------------
__global__ __launch_bounds__(256) void k7d_sig(const float* __restrict__ si12,
  const float* __restrict__ mean, const float* __restrict__ rstd,
  const float* __restrict__ w2, const float* __restrict__ b2, float* __restrict__ sig)
{
    int bv=blockIdx.x*256+threadIdx.x;
    int b=bv>>15;
    float a=b2[0];
    #pragma unroll
    for(int c=0;c<12;c++){
        float t=(si12[(size_t)bv*12+c]-mean[b*12+c])*rstd[b*12+c];
        a+=gelu_f(t)*w2[c];
    }
    sig[bv]=sigmoid_f(a);
}

// ---------------- K8: stats of sigmoid(si)*PJ (per b,c of 96) ----------------
__global__ __launch_bounds__(192) void k8_gstats(const float* __restrict__ pj,
   const float* __restrict__ sig, float* __restrict__ gSum, float* __restrict__ gSumsq)
{
    int tid=threadIdx.x; int c=tid%96, vh=tid/96;
    int chunk=blockIdx.x, b=blockIdx.y;
    float s=0.f,ss=0.f;
    for(int i=0;i<128;i++){
        int v=chunk*256 + i*2 + vh;
        int bv=(b<<15)+v;
        float t=sig[bv]*pj[(size_t)bv*96+c];
        s+=t; ss+=t*t;
    }
    atomicAdd(&gSum[b*96+c],s); atomicAdd(&gSumsq[b*96+c],ss);
}

// ---------------- Kprep: w_proj (192x192 f32, [k][n]) -> WT bf16 [n][k] ----------------
__global__ __launch_bounds__(256) void kprep(const float* __restrict__ wp,
                                             __hip_bfloat16* __restrict__ WT)
{
    int i=blockIdx.x*256+threadIdx.x;     // 36864 total
    int n=i/192, k=i-n*192;
    WT[n*192+k]=__float2bfloat16(wp[k*192+n]);
}

// ---------------- K9a2: LN(attn) + gated-inorm -> U (bf16, in-place over ATO) ----------------
// Row r: reads ato[r*96 .. r*96+96) (f32, 384B) and writes U row r as 192 bf16 over the
// SAME 384 bytes. The 8 lanes owning a row are in one wave; all f32 loads are issued
// before any bf16 store in program order -> wave-lockstep safe.
__global__ __launch_bounds__(256) void k9a2_gather(float* atoU,
  const float* __restrict__ pj, const float* __restrict__ sig,
  const float* __restrict__ gMean, const float* __restrict__ gRstd,
  const float* __restrict__ ga, const float* __restrict__ bba)
{
    int tid=threadIdx.x; int row0=blockIdx.x*32;
    int rr=tid>>3, part=tid&7;
    int r=row0+rr;
    __hip_bfloat16* U=(__hip_bfloat16*)atoU;
    float av[12];
    #pragma unroll
    for(int j=0;j<12;j++) av[j]=atoU[(size_t)r*96+part*12+j];
    float s=0.f, ss=0.f;
    #pragma unroll
    for(int j=0;j<12;j++){ s+=av[j]; ss+=av[j]*av[j]; }
    #pragma unroll
    for(int o=1;o<8;o<<=1){ s+=__shfl_xor(s,o); ss+=__shfl_xor(ss,o); }
    float m=s*(1.f/96.f), var=ss*(1.f/96.f)-m*m, rstd=rsqrtf(var+EPS);
    // gated instance-normalized cnn half: compute BEFORE overwriting (pj is a separate buffer)
    int bv=row_to_bv(r); int b=bv>>15;
    float sg=sig[bv];
    float cv[12];
    #pragma unroll
    for(int j=0;j<12;j++){
        int c=part*12+j;
        float t=sg*pj[(size_t)bv*96+c];
        cv[j]=(t-gMean[b*96+c])*gRstd[b*96+c];
    }
    #pragma unroll
    for(int j=0;j<12;j++){
        int c=part*12+j;
        U[(size_t)r*192+c]=__float2bfloat16((av[j]-m)*rstd*ga[c]+bba[c]);
    }
    #pragma unroll
    for(int j=0;j<12;j++){
        int c=part*12+j;
        U[(size_t)r*192+96+c]=__float2bfloat16(cv[j]);
    }
}

// ---------------- K9b: final 192x192 projection via bf16 MFMA (no LDS, no barriers) ----------------
// C[m][n] = sum_k U[m][k] * WT[n][k]  (gemm_bt convention).
// Frags: A row m=lane&15 of U, B row n=lane&15 of WT, 8 contiguous k at quad*8.
// C/D: col=lane&15 (n), row=quad*4+reg (m).
__global__ __launch_bounds__(256) void k9b_mfma(const __hip_bfloat16* __restrict__ Ubf,
   const __hip_bfloat16* __restrict__ WT, const float* __restrict__ bp,
   float* __restrict__ out)
{
    int tid=threadIdx.x;
    int wave=tid>>6, lane=tid&63;
    int quad=lane>>4, l16=lane&15;
    int rowA = blockIdx.x*64 + wave*16 + l16;
    const short* Us=(const short*)Ubf;
    const short* Ws=(const short*)WT;
    f32x4 acc[12];
    #pragma unroll
    for(int j=0;j<12;j++) acc[j]=(f32x4){0.f,0.f,0.f,0.f};
    #pragma unroll
    for(int t=0;t<6;t++){
        int k0=t*32;
        short8 a = *(const short8*)(Us + (size_t)rowA*192 + k0 + quad*8);
        #pragma unroll
        for(int j=0;j<12;j++){
            short8 bfr = *(const short8*)(Ws + (size_t)(j*16+l16)*192 + k0 + quad*8);
            acc[j]=__builtin_amdgcn_mfma_f32_16x16x32_bf16(a,bfr,acc[j],0,0,0);
        }
    }
    int mbase = blockIdx.x*64 + wave*16 + quad*4;
    #pragma unroll
    for(int j=0;j<12;j++){
        int n=j*16+l16;
        float bias=bp[n];
        #pragma unroll
        for(int r2=0;r2<4;r2++){
            out[(size_t)(mbase+r2)*192 + n] = acc[j][r2] + bias;
        }
    }
}

extern "C" void kernel_launch(void* const* d_in, const int* in_sizes, int n_in,
                              void* d_out, int out_size, void* d_ws, size_t ws_size,
                              hipStream_t stream)
{
    const float* x      =(const float*)d_in[0];
    const float* w_pattn=(const float*)d_in[1];
    const float* b_pattn=(const float*)d_in[2];
    const float* g_aln  =(const float*)d_in[3];
    const float* b_aln  =(const float*)d_in[4];
    const float* w_pcnn =(const float*)d_in[5];
    const float* b_pcnn =(const float*)d_in[6];
    const float* g_cln  =(const float*)d_in[7];
    const float* b_cln  =(const float*)d_in[8];
    const float* dw_w   =(const float*)d_in[9];
    const float* dw_b   =(const float*)d_in[10];
    const float* ci_w1  =(const float*)d_in[11];
    const float* ci_b1  =(const float*)d_in[12];
    const float* ci_w2  =(const float*)d_in[13];
    const float* ci_b2  =(const float*)d_in[14];
    const float* pj_w   =(const float*)d_in[15];
    const float* pj_b   =(const float*)d_in[16];
    const float* qkv_w  =(const float*)d_in[17];
    const float* qkv_b  =(const float*)d_in[18];
    const float* si_w1  =(const float*)d_in[19];
    const float* si_b1  =(const float*)d_in[20];
    const float* si_w2  =(const float*)d_in[21];
    const float* si_b2  =(const float*)d_in[22];
    const float* g_anorm=(const float*)d_in[23];
    const float* b_anorm=(const float*)d_in[24];
    const float* w_proj =(const float*)d_in[25];
    const float* b_proj =(const float*)d_in[26];
    const float* rpb    =(const float*)d_in[27];
    (void)in_sizes; (void)n_in; (void)out_size; (void)ws_size;

    float* ws  =(float*)d_ws;
    float* vol =(float*)d_out;            // volume lives in d_out until k9b_mfma overwrites
    // ws float offsets. NOTE: VOLA spans [12,582,912, 37,748,736) while live (k1->k2);
    // QKV (bf16) spans float slots [12,582,912, 31,457,280) while live (kqkv->k6).
    // Anything inside VOLA's span may be written ONLY after k2; anything inside QKV's
    // span only after k6 (except Z0/NZ/WTQ, which sit past QKV's end).
    float* XA   = ws;                     // [0, 12,582,912)  -> ATO after k6 -> U (bf16) after k9a2
    float* VOLA = ws + 12582912;          // LN'd cnn volume (dead after k2)
    __hip_bfloat16* QKV = (__hip_bfloat16*)(ws + 12582912);  // overlays dead VOLA after K2
    float* PJ   = ws + 12582912;          // overlays dead QKV after K6
    float* SI12 = ws + 25165824;          // [25,165,824, 26,738,688) (written at k7a, after k6)
    float* SIG  = ws + 26738688;          // [26,738,688, 26,869,760)
    __hip_bfloat16* WT = (__hip_bfloat16*)(ws + 25165824); // overlays SI12 AFTER k7d_sig (18,432 float slots)
    // WTp (pj weights hi/lo, 18,432 floats) in the post-k6 dead zone right after SIG:
    // [26,869,760, 26,888,192) — inside dead-QKV span, written by kprepp AFTER k6_attn.
    __hip_bfloat16* WTPHI = (__hip_bfloat16*)(ws + 26869760);
    __hip_bfloat16* WTPLO = WTPHI + 18432;
    float* Z0   = ws + 31457280;          // zeroed accumulators (3168 floats)
    float* IN_SUM   = Z0;        float* IN_SUMSQ = Z0+768;
    float* POOLED   = Z0+1536;
    float* SI_SUM   = Z0+2304;   float* SI_SUMSQ = Z0+2352;
    float* G_SUM    = Z0+2400;   float* G_SUMSQ  = Z0+2784;
    float* NZ   = ws + 31460448;
    float* IN_MEAN  = NZ;        float* IN_RSTD  = NZ+768;
    float* GATE     = NZ+1536;
    float* SI_MEAN  = NZ+1920;   float* SI_RSTD  = NZ+1968;
    float* G_MEAN   = NZ+2016;   float* G_RSTD   = NZ+2400;
    // qkv weights hi/lo (27,648 floats): [31,463,248, 31,490,896). Past QKV's end and
    // past Z0/NZ, but INSIDE VOLA's span -> must be written AFTER k2 (VOLA death).
    __hip_bfloat16* WTQHI = (__hip_bfloat16*)(ws + 31463248);
    __hip_bfloat16* WTQLO = WTQHI + 27648;

    // 0. weight prep for K1 -> d_out (dead until k2)
    __hip_bfloat16* WT1hi=(__hip_bfloat16*)d_out;            // 55,296 bf16
    __hip_bfloat16* WT1lo=WT1hi+55296;                       // 55,296 bf16 (ends @ 221,184 B)
    kprep1<<<216,256,0,stream>>>(w_pattn,w_pcnn,WT1hi,WT1lo);
    // 1. dual GEMM + LNs via split-bf16 MFMA (LDS-staged B, reg-A)
    k1_mfma<<<2048,256,0,stream>>>(x,WT1hi,WT1lo,b_pattn,g_aln,b_aln,
                                   b_pcnn,g_cln,b_cln,XA,VOLA);
    // 2. depthwise conv -> d_out (overwrites WT1hi/lo, which are dead after k1)
    k2_dwconv<<<4096,192,0,stream>>>(VOLA,dw_w,dw_b,vol);
    // zero accumulators + qkv weight prep (both regions inside VOLA span -> only
    // safe to write now, after k2)
    hipMemsetAsync((void*)Z0, 0, 3168*sizeof(float), stream);
    kprepq<<<108,256,0,stream>>>(qkv_w,WTQHI,WTQLO);
    // 3. instance norm stats + finalize
    k3_stats<<<dim3(128,4),192,0,stream>>>(vol,IN_SUM,IN_SUMSQ);
    k_finalize<<<3,256,0,stream>>>(IN_SUM,IN_SUMSQ,IN_MEAN,IN_RSTD,768,1.f/32768.f);
    // 4. in-place inorm+gelu + pooled ; gate MLP
    k4_apply<<<dim3(128,4),192,0,stream>>>(vol,IN_MEAN,IN_RSTD,POOLED);
    k4b_gate<<<4,128,0,stream>>>(POOLED,ci_w1,ci_b1,ci_w2,ci_b2,GATE);
    // 5. QKV GEMM via split-bf16 MFMA (bf16 out, gate/scale folded)
    kqkv<<<2048,256,0,stream>>>(XA,WTQHI,WTQLO,qkv_b,GATE,QKV);
    // 6. attention via MFMA (writes ATO over dead XA)
    k6_attn<<<2048,256,0,stream>>>(QKV,rpb,XA);
    // 7. pj weight prep (region is dead-QKV, safe only after k6), then 1x1 conv 192->96
    kprepp<<<72,256,0,stream>>>(pj_w,WTPHI,WTPLO);
    k5_pj<<<2048,256,0,stream>>>(vol,WTPHI,WTPLO,pj_b,PJ);
    // 8. spatial-interaction path
    k7a_si<<<2048,192,0,stream>>>(XA,si_w1,si_b1,SI12,SI_SUM,SI_SUMSQ);
    k_finalize<<<1,64,0,stream>>>(SI_SUM,SI_SUMSQ,SI_MEAN,SI_RSTD,48,1.f/32768.f);
    k7d_sig<<<512,256,0,stream>>>(SI12,SI_MEAN,SI_RSTD,si_w2,si_b2,SIG);
    // weight transpose/cast for the final MFMA GEMM (overlays SI12, which is now dead)
    kprep<<<144,256,0,stream>>>(w_proj,WT);
    // 9. gated-cnn instance norm stats
    k8_gstats<<<dim3(128,4),192,0,stream>>>(PJ,SIG,G_SUM,G_SUMSQ);
    k_finalize<<<2,256,0,stream>>>(G_SUM,G_SUMSQ,G_MEAN,G_RSTD,384,1.f/32768.f);
    // 10a. LN(attn) + gated inorm -> U bf16, in-place over ATO (ws). d_out untouched.
    k9a2_gather<<<4096,256,0,stream>>>(XA,PJ,SIG,G_MEAN,G_RSTD,g_anorm,b_anorm);
    // 10b. final projection GEMM via MFMA -> d_out (only epilogue stores touch d_out)
    k9b_mfma<<<2048,256,0,stream>>>((const __hip_bfloat16*)XA,WT,b_proj,vol);
}